// Round 16
// baseline (310.197 us; speedup 1.0000x reference)
//
#include <hip/hip_runtime.h>
#include <hip/hip_bf16.h>

#define B_N 16
#define LP_N 1024
#define LQ_N 1024
#define H_N 1024

typedef unsigned short u16;
typedef __attribute__((ext_vector_type(8))) _Float16 f16x8;
typedef __attribute__((ext_vector_type(4))) float f32x4;

__device__ __forceinline__ u16 f2h(float x) {
    _Float16 h = (_Float16)x;
    return *(u16*)&h;
}
__device__ __forceinline__ float h2f(u16 u) {
    _Float16 h;
    *(u16*)&h = u;
    return (float)h;
}

__device__ __forceinline__ void load_lds16(const u16* g, u16* l) {
    __builtin_amdgcn_global_load_lds(
        (const __attribute__((address_space(1))) void*)g,
        (__attribute__((address_space(3))) void*)l, 16, 0, 0);
}

#define MFMA_F16(a, b, c) __builtin_amdgcn_mfma_f32_16x16x32_f16(a, b, c, 0, 0, 0)
#define VMW0()  asm volatile("s_waitcnt vmcnt(0)" ::: "memory")
#define LGKM8() asm volatile("s_waitcnt lgkmcnt(8)" ::: "memory")
#define LGKM0() asm volatile("s_waitcnt lgkmcnt(0)" ::: "memory")
#define SCHB()  __builtin_amdgcn_sched_barrier(0)
#define SBAR()  __builtin_amdgcn_s_barrier()

// ---------------------------------------------------------------------------
// GEMM1 kernel (R13/R15-verified, unchanged): 256x256 fp16 split, BK=32,
// 3 regions {A_hi, A_lo, B} staged once/tile, one vmcnt(0)+s_barrier gate.
// ---------------------------------------------------------------------------
template<bool SPLIT, int EPI>
__launch_bounds__(512, 2)
__global__ void gemm2t(const u16* __restrict__ Ahi, const u16* __restrict__ Alo,
                       const u16* __restrict__ Bm,
                       const float* __restrict__ bias,
                       float* __restrict__ Cf, u16* __restrict__ Ch,
                       int N, int gn, int gmn,
                       long long sA, long long sB, long long sC)
{
    constexpr int REG  = 8192;
    constexpr int O_AL = REG;
    constexpr int O_B  = SPLIT ? 2 * REG : REG;
    constexpr int BUF  = SPLIT ? 3 * REG : 2 * REG;
    __shared__ __align__(16) u16 lds[2 * BUF];

    const int tid  = threadIdx.x;
    const int lane = tid & 63;
    const int wv   = tid >> 6;
    const int wr   = wv >> 2, wc = wv & 3;

    const int d   = blockIdx.x;
    const int cpx = gridDim.x >> 3;
    const int swz = (d & 7) * cpx + (d >> 3);
    const long long z = swz / gmn;
    const int r_  = swz % gmn;
    const int bm  = (r_ / gn) * 256;
    const int bn  = (r_ % gn) * 256;

    const char* pAh = (const char*)(Ahi + z * sA);
    const char* pAl = (const char*)(Alo + z * sA);
    const char* pB  = (const char*)(Bm + z * sB);

    const int r0 = tid >> 2;
    const int xc = (tid & 3) ^ ((r0 >> 1) & 3);
    const long long aof = (long long)(bm + r0) * 2048 + xc * 16;
    const long long bof = (long long)(bn + r0) * 2048 + xc * 16;
    const long long ao2 = aof + 128 * 2048;
    const long long bo2 = bof + 128 * 2048;
    const int d0 = tid * 8;
    const int d1 = d0 + 4096;

    int offA[8], offB[4];
#pragma unroll
    for (int i = 0; i < 8; ++i) {
        const int r = wr * 128 + i * 16 + (lane & 15);
        offA[i] = r * 32 + ((((lane >> 4) ^ (r >> 1)) & 3) << 3);
    }
#pragma unroll
    for (int j = 0; j < 4; ++j) {
        const int r = wc * 64 + j * 16 + (lane & 15);
        offB[j] = r * 32 + ((((lane >> 4) ^ (r >> 1)) & 3) << 3);
    }

    f32x4 acc[8][4];
#pragma unroll
    for (int i = 0; i < 8; ++i)
#pragma unroll
        for (int j = 0; j < 4; ++j)
            acc[i][j] = (f32x4){0.f, 0.f, 0.f, 0.f};

#define STG(NB, KB) do {                                                      \
        load_lds16((const u16*)(pAh + aof + (KB)), lds + (NB) + d0);          \
        load_lds16((const u16*)(pAh + ao2 + (KB)), lds + (NB) + d1);          \
        load_lds16((const u16*)(pB + bof + (KB)), lds + (NB) + O_B + d0);     \
        load_lds16((const u16*)(pB + bo2 + (KB)), lds + (NB) + O_B + d1);     \
        if constexpr (SPLIT) {                                                \
            load_lds16((const u16*)(pAl + aof + (KB)), lds + (NB) + O_AL + d0); \
            load_lds16((const u16*)(pAl + ao2 + (KB)), lds + (NB) + O_AL + d1); \
        }                                                                     \
    } while (0)

#define TERM(AF, BF) do {                                                     \
        __builtin_amdgcn_s_setprio(1);                                        \
        _Pragma("unroll")                                                     \
        for (int i = 0; i < 8; ++i)                                           \
            _Pragma("unroll")                                                 \
            for (int j = 0; j < 4; ++j)                                       \
                acc[i][j] = MFMA_F16(AF[i], BF[j], acc[i][j]);                \
        __builtin_amdgcn_s_setprio(0);                                        \
    } while (0)

    constexpr int NT = 32;

    STG(0, 0);

    for (int t = 0; t < NT; ++t) {
        const int cb = (t & 1) ? BUF : 0;
        const int nb = (t & 1) ? 0 : BUF;
        const long long kb = (long long)(t + 1) * 64;

        VMW0();
        SBAR();
        f16x8 b[4], ah[8], al[8];
#pragma unroll
        for (int j = 0; j < 4; ++j)
            b[j] = *(const f16x8*)(lds + cb + O_B + offB[j]);
#pragma unroll
        for (int i = 0; i < 8; ++i)
            ah[i] = *(const f16x8*)(lds + cb + offA[i]);
        if constexpr (SPLIT) {
#pragma unroll
            for (int i = 0; i < 8; ++i)
                al[i] = *(const f16x8*)(lds + cb + O_AL + offA[i]);
        }
        if (t + 1 < NT) STG(nb, kb);
        if constexpr (SPLIT) { LGKM8(); } else { LGKM0(); }
        SCHB();
        TERM(ah, b);
        if constexpr (SPLIT) {
            LGKM0(); SCHB();
            TERM(al, b);
        }
    }
#undef STG
#undef TERM

    const long long Cbase = z * sC;
#pragma unroll
    for (int i = 0; i < 8; ++i) {
        const int row0 = bm + wr * 128 + i * 16 + ((lane >> 4) << 2);
#pragma unroll
        for (int j = 0; j < 4; ++j) {
            const int col = bn + wc * 64 + j * 16 + (lane & 15);
#pragma unroll
            for (int e = 0; e < 4; ++e) {
                const float v = acc[i][j][e];
                const long long idx = Cbase + (long long)(row0 + e) * N + col;
                if constexpr (EPI == 0) {
                    Cf[idx] = v;
                } else if constexpr (EPI == 1) {
                    Ch[idx] = f2h(v + bias[col]);
                } else {
                    Cf[idx] = fmaxf(v, 0.f);
                }
            }
        }
    }
}

// ---------------------------------------------------------------------------
// R16 dense GEMM: A direct global->register (wave-private rows, prefetched
// one tile ahead via two NAMED reg sets aP/aQ, loop unrolled x2 per rule
// #20), B-only LDS staging (16KB/tile, dbuf 32KB). Per tile the serial
// chain shrinks: ds_reads/wave 12->4 b128, staged bytes halved, vmcnt set
// 10/thread. The 4 waves sharing wr issue identical A addresses -> L1
// serves repeats (16KB/tile per wr-group fits 32KB L1). Compiler inserts
// the vmcnt wait before MFMA use of aP/aQ (auto-waitcnt on load results);
// explicit VMW0 at tile top covers the B staging. BK=32, 256x256, NT=32.
// Swizzle: R13-verified (row>>1)&3 family on both sides, 0 conflicts.
// EPI: 0 = fp32 store, 2 = relu fp32 store.
// ---------------------------------------------------------------------------
template<int EPI>
__launch_bounds__(512, 1)
__global__ void gemm_da(const u16* __restrict__ Am, const u16* __restrict__ Bm,
                        float* __restrict__ Cf,
                        int N, int gn, int gmn,
                        long long sA, long long sB, long long sC)
{
    constexpr int BUF = 8192;                    // u16: 256x32 B region (16KB)
    __shared__ __align__(16) u16 lds[2 * BUF];

    const int tid  = threadIdx.x;
    const int lane = tid & 63;
    const int wv   = tid >> 6;
    const int wr   = wv >> 2, wc = wv & 3;

    const int d   = blockIdx.x;
    const int cpx = gridDim.x >> 3;
    const int swz = (d & 7) * cpx + (d >> 3);
    const long long z = swz / gmn;
    const int r_  = swz % gmn;
    const int bm  = (r_ / gn) * 256;
    const int bn  = (r_ % gn) * 256;

    const char* pA = (const char*)(Am + z * sA);
    const char* pB = (const char*)(Bm + z * sB);

    // B staging (R13-verified geometry): 1024 chunks, 2/thread.
    const int r0 = tid >> 2;
    const int xc = (tid & 3) ^ ((r0 >> 1) & 3);
    const long long bof  = (long long)(bn + r0) * 2048 + xc * 16;
    const long long bof2 = bof + 128 * 2048;
    const int d0 = tid * 8;
    const int d1 = d0 + 4096;

    // B frag ds_read offsets (same swizzle)
    int offB[4];
#pragma unroll
    for (int j = 0; j < 4; ++j) {
        const int r = wc * 64 + j * 16 + (lane & 15);
        offB[j] = r * 32 + ((((lane >> 4) ^ (r >> 1)) & 3) << 3);
    }

    // A direct: frag i reads A[bm + wr*128 + i*16 + (lane&15)][t*32 + (lane>>4)*8 .. +8]
    const long long aoff0 = (long long)(bm + wr * 128 + (lane & 15)) * 2048
                          + ((lane >> 4) << 4);

    f32x4 acc[8][4];
#pragma unroll
    for (int i = 0; i < 8; ++i)
#pragma unroll
        for (int j = 0; j < 4; ++j)
            acc[i][j] = (f32x4){0.f, 0.f, 0.f, 0.f};

    f16x8 aP[8], aQ[8];

#define STGB(NB, KB) do {                                                     \
        load_lds16((const u16*)(pB + bof  + (KB)), lds + (NB) + d0);          \
        load_lds16((const u16*)(pB + bof2 + (KB)), lds + (NB) + d1);          \
    } while (0)

#define LOADA(DST, KB) do {                                                   \
        _Pragma("unroll")                                                     \
        for (int i = 0; i < 8; ++i)                                           \
            DST[i] = *(const f16x8*)(pA + aoff0 + (long long)i * 32768 + (KB)); \
    } while (0)

#define RD_B(B_, CB) do {                                                     \
        _Pragma("unroll")                                                     \
        for (int j = 0; j < 4; ++j)                                           \
            B_[j] = *(const f16x8*)(lds + (CB) + offB[j]);                    \
    } while (0)

#define TERM(AF, BF) do {                                                     \
        __builtin_amdgcn_s_setprio(1);                                        \
        _Pragma("unroll")                                                     \
        for (int i = 0; i < 8; ++i)                                           \
            _Pragma("unroll")                                                 \
            for (int j = 0; j < 4; ++j)                                       \
                acc[i][j] = MFMA_F16(AF[i], BF[j], acc[i][j]);                \
        __builtin_amdgcn_s_setprio(0);                                        \
    } while (0)

    constexpr int NT = 32;

    // prologue: tile 0 -> buf0 + aP
    STGB(0, 0);
    LOADA(aP, 0);

    for (int t = 0; t < NT; t += 2) {
        // body A: tile t (even) from buf0/aP; prefetch t+1 -> buf1/aQ
        {
            VMW0();              // B(t) in LDS; aP landed (also compiler-auto)
            SBAR();
            f16x8 b[4];
            RD_B(b, 0);
            if (t + 1 < NT) {
                const long long kb = (long long)(t + 1) * 64;
                STGB(BUF, kb);
                LOADA(aQ, kb);
            }
            LGKM0(); SCHB();
            TERM(aP, b);
        }
        // body B: tile t+1 (odd) from buf1/aQ; prefetch t+2 -> buf0/aP
        {
            VMW0();
            SBAR();
            f16x8 b[4];
            RD_B(b, BUF);
            if (t + 2 < NT) {
                const long long kb = (long long)(t + 2) * 64;
                STGB(0, kb);
                LOADA(aP, kb);
            }
            LGKM0(); SCHB();
            TERM(aQ, b);
        }
    }
#undef STGB
#undef LOADA
#undef RD_B
#undef TERM

    // epilogue; C/D map: col = lane&15, row = (lane>>4)*4 + e  [m89/m91]
    const long long Cbase = z * sC;
#pragma unroll
    for (int i = 0; i < 8; ++i) {
        const int row0 = bm + wr * 128 + i * 16 + ((lane >> 4) << 2);
#pragma unroll
        for (int j = 0; j < 4; ++j) {
            const int col = bn + wc * 64 + j * 16 + (lane & 15);
#pragma unroll
            for (int e = 0; e < 4; ++e) {
                const float v = acc[i][j][e];
                const long long idx = Cbase + (long long)(row0 + e) * N + col;
                if constexpr (EPI == 0) Cf[idx] = v;
                else                    Cf[idx] = fmaxf(v, 0.f);
            }
        }
    }
}

// fp32 -> fp16 single, 4 elems/thread (p pre-pass)
__global__ void cvt_f16(const float* __restrict__ in, u16* __restrict__ o16,
                        long long n4)
{
    const long long i = (long long)blockIdx.x * 256 + threadIdx.x;
    if (i >= n4) return;
    const float4 v = ((const float4*)in)[i];
    ushort4 h;
    h.x = f2h(v.x); h.y = f2h(v.y); h.z = f2h(v.z); h.w = f2h(v.w);
    ((ushort4*)o16)[i] = h;
}

// fused q pre-pass: q_hi, q_lo (straight) and qT (transposed)
__global__ void fuse_cvt_q(const float* __restrict__ q, u16* __restrict__ hi,
                           u16* __restrict__ lo, u16* __restrict__ thi)
{
    __shared__ float t[32][33];
    const long long z = blockIdx.z;
    const long long base = z * 1048576;
    const int r0 = blockIdx.y * 32, c0 = blockIdx.x * 32;
    for (int j = threadIdx.y; j < 32; j += 8) {
        const float v = q[base + (long long)(r0 + j) * 1024 + c0 + threadIdx.x];
        t[j][threadIdx.x] = v;
        const long long o = base + (long long)(r0 + j) * 1024 + c0 + threadIdx.x;
        const u16 h = f2h(v);
        hi[o] = h;
        lo[o] = f2h(v - h2f(h));
    }
    __syncthreads();
    for (int j = threadIdx.y; j < 32; j += 8)
        thi[base + (long long)(c0 + j) * 1024 + r0 + threadIdx.x] = f2h(t[threadIdx.x][j]);
}

// Wt[c][r] = W[r][c], fp16 single
__global__ void transpose_cvt_w(const float* __restrict__ in, u16* __restrict__ hi)
{
    __shared__ float t[32][33];
    const int r0 = blockIdx.y * 32, c0 = blockIdx.x * 32;
    for (int j = threadIdx.y; j < 32; j += 8)
        t[j][threadIdx.x] = in[(long long)(r0 + j) * 1024 + c0 + threadIdx.x];
    __syncthreads();
    for (int j = threadIdx.y; j < 32; j += 8)
        hi[(long long)(c0 + j) * 1024 + r0 + threadIdx.x] = f2h(t[threadIdx.x][j]);
}

// row softmax (fp32 in, fp16 out)
__global__ void softmax_f16(const float* __restrict__ S, u16* __restrict__ A)
{
    const long long row = blockIdx.x;
    const float* r = S + row * (long long)LQ_N;
    const int t = threadIdx.x;
    float4 v = ((const float4*)r)[t];

    float m = fmaxf(fmaxf(v.x, v.y), fmaxf(v.z, v.w));
#pragma unroll
    for (int off = 32; off > 0; off >>= 1)
        m = fmaxf(m, __shfl_xor(m, off));

    __shared__ float red[4];
    const int lane = t & 63, wid = t >> 6;
    if (lane == 0) red[wid] = m;
    __syncthreads();
    m = fmaxf(fmaxf(red[0], red[1]), fmaxf(red[2], red[3]));
    __syncthreads();

    v.x = __expf(v.x - m); v.y = __expf(v.y - m);
    v.z = __expf(v.z - m); v.w = __expf(v.w - m);
    float s = v.x + v.y + v.z + v.w;
#pragma unroll
    for (int off = 32; off > 0; off >>= 1)
        s += __shfl_xor(s, off);
    if (lane == 0) red[wid] = s;
    __syncthreads();
    s = red[0] + red[1] + red[2] + red[3];

    const float inv = 1.0f / s;
    ushort4 o;
    o.x = f2h(v.x * inv); o.y = f2h(v.y * inv);
    o.z = f2h(v.z * inv); o.w = f2h(v.w * inv);
    ((ushort4*)(A + row * (long long)LQ_N))[t] = o;
}

// ---------------------------------------------------------------------------
// Fallback fp32 path (round-1, verified; needs only 128 MB ws)
// ---------------------------------------------------------------------------
#define BM 128
#define BN 128
#define BK 8
#define TM 8
#define TN 8

template<bool TRANSB, bool BIAS, bool RELU>
__launch_bounds__(256)
__global__ void gemm_k(const float* __restrict__ A, const float* __restrict__ Bmat,
                       const float* __restrict__ bias, float* __restrict__ C,
                       int M, int N, int K,
                       long long sA, long long sB, long long sC)
{
    __shared__ float As[BK][BM];
    __shared__ float Bs[BK][BN];
    const int tid = threadIdx.x;
    const int tx = tid & 15;
    const int ty = tid >> 4;
    const int bn = blockIdx.x * BN;
    const int bm = blockIdx.y * BM;
    const long long z = blockIdx.z;
    A += z * sA; Bmat += z * sB; C += z * sC;
    float acc[TM][TN];
#pragma unroll
    for (int i = 0; i < TM; i++)
#pragma unroll
        for (int j = 0; j < TN; j++) acc[i][j] = 0.f;
    const int arow = tid >> 1;
    const int acol = (tid & 1) * 4;
    const int bk_n = tid >> 5;
    const int bn_n = (tid & 31) * 4;
    for (int k0 = 0; k0 < K; k0 += BK) {
        float4 a4 = *(const float4*)&A[(long long)(bm + arow) * K + k0 + acol];
        As[acol + 0][arow] = a4.x; As[acol + 1][arow] = a4.y;
        As[acol + 2][arow] = a4.z; As[acol + 3][arow] = a4.w;
        if (TRANSB) {
            float4 b4 = *(const float4*)&Bmat[(long long)(bn + arow) * K + k0 + acol];
            Bs[acol + 0][arow] = b4.x; Bs[acol + 1][arow] = b4.y;
            Bs[acol + 2][arow] = b4.z; Bs[acol + 3][arow] = b4.w;
        } else {
            float4 b4 = *(const float4*)&Bmat[(long long)(k0 + bk_n) * N + bn + bn_n];
            *(float4*)&Bs[bk_n][bn_n] = b4;
        }
        __syncthreads();
#pragma unroll
        for (int k = 0; k < BK; k++) {
            float a[TM], b[TN];
            *(float4*)&a[0] = *(const float4*)&As[k][ty * TM];
            *(float4*)&a[4] = *(const float4*)&As[k][ty * TM + 4];
            *(float4*)&b[0] = *(const float4*)&Bs[k][tx * TN];
            *(float4*)&b[4] = *(const float4*)&Bs[k][tx * TN + 4];
#pragma unroll
            for (int i = 0; i < TM; i++)
#pragma unroll
                for (int j = 0; j < TN; j++)
                    acc[i][j] = fmaf(a[i], b[j], acc[i][j]);
        }
        __syncthreads();
    }
#pragma unroll
    for (int i = 0; i < TM; i++) {
        const int row = bm + ty * TM + i;
#pragma unroll
        for (int j = 0; j < TN; j += 4) {
            const int col = bn + tx * TN + j;
            float4 v;
            v.x = acc[i][j + 0]; v.y = acc[i][j + 1];
            v.z = acc[i][j + 2]; v.w = acc[i][j + 3];
            if (BIAS) {
                v.x += bias[col + 0]; v.y += bias[col + 1];
                v.z += bias[col + 2]; v.w += bias[col + 3];
            }
            if (RELU) {
                v.x = fmaxf(v.x, 0.f); v.y = fmaxf(v.y, 0.f);
                v.z = fmaxf(v.z, 0.f); v.w = fmaxf(v.w, 0.f);
            }
            *(float4*)&C[(long long)row * N + col] = v;
        }
    }
}

__global__ void softmax_k(float* __restrict__ S)
{
    const long long row = blockIdx.x;
    float* r = S + row * (long long)LQ_N;
    const int t = threadIdx.x;
    float4 v = ((float4*)r)[t];
    float m = fmaxf(fmaxf(v.x, v.y), fmaxf(v.z, v.w));
#pragma unroll
    for (int off = 32; off > 0; off >>= 1)
        m = fmaxf(m, __shfl_xor(m, off));
    __shared__ float red[4];
    const int lane = t & 63, wid = t >> 6;
    if (lane == 0) red[wid] = m;
    __syncthreads();
    m = fmaxf(fmaxf(red[0], red[1]), fmaxf(red[2], red[3]));
    __syncthreads();
    v.x = __expf(v.x - m); v.y = __expf(v.y - m);
    v.z = __expf(v.z - m); v.w = __expf(v.w - m);
    float s = v.x + v.y + v.z + v.w;
#pragma unroll
    for (int off = 32; off > 0; off >>= 1)
        s += __shfl_xor(s, off);
    if (lane == 0) red[wid] = s;
    __syncthreads();
    s = red[0] + red[1] + red[2] + red[3];
    const float inv = 1.0f / s;
    v.x *= inv; v.y *= inv; v.z *= inv; v.w *= inv;
    ((float4*)r)[t] = v;
}

extern "C" void kernel_launch(void* const* d_in, const int* in_sizes, int n_in,
                              void* d_out, int out_size, void* d_ws, size_t ws_size,
                              hipStream_t stream)
{
    const float* p    = (const float*)d_in[0];
    const float* q    = (const float*)d_in[1];
    const float* W    = (const float*)d_in[2];
    const float* bias = (const float*)d_in[3];
    float* out = (float*)d_out;

    const size_t MB32 = 33554432ull;                 // 16M fp16
    const size_t NEED = 5 * MB32 + 2097152ull;       // 160 MB + 2 MB

    if (ws_size >= NEED) {
        char* w = (char*)d_ws;
        u16* p16   = (u16*)(w + 0 * MB32);
        u16* q_hi  = (u16*)(w + 1 * MB32);
        u16* q_lo  = (u16*)(w + 2 * MB32);
        u16* keys  = (u16*)(w + 3 * MB32);
        u16* qT    = (u16*)(w + 4 * MB32);
        u16* Wt    = (u16*)(w + 5 * MB32);
        float* scores = (float*)(w + 1 * MB32);  // reuses q_hi/q_lo after GEMM1
        u16* attn     = (u16*)(w + 0 * MB32);    // reuses p16 after GEMM2

        const long long n4 = (long long)B_N * LQ_N * H_N / 4;
        cvt_f16<<<dim3((unsigned)(n4 / 256)), 256, 0, stream>>>(p, p16, n4);
        fuse_cvt_q<<<dim3(32, 32, B_N), dim3(32, 8), 0, stream>>>(q, q_hi, q_lo, qT);
        transpose_cvt_w<<<dim3(32, 32, 1), dim3(32, 8), 0, stream>>>(W, Wt);

        // keys = (q_hi + q_lo) @ Wt + b : BK32 split (R15-verified config).
        gemm2t<true, 1><<<256, 512, 0, stream>>>(
            q_hi, q_lo, Wt, bias, nullptr, keys,
            H_N, /*gn=*/4, /*gmn=*/256, 0, 0, 0);

        // scores[b] = p16[b] @ keys[b]^T : A-direct dense.
        gemm_da<0><<<256, 512, 0, stream>>>(
            p16, keys, scores,
            LQ_N, /*gn=*/4, /*gmn=*/16,
            (long long)LP_N * H_N, (long long)LQ_N * H_N, (long long)LP_N * LQ_N);

        softmax_f16<<<B_N * LP_N, 256, 0, stream>>>(scores, attn);

        // out[b] = relu(attn[b] @ q[b]) : A-direct dense.
        gemm_da<2><<<256, 512, 0, stream>>>(
            attn, qT, out,
            H_N, /*gn=*/4, /*gmn=*/16,
            (long long)LP_N * LQ_N, (long long)H_N * LQ_N, (long long)LP_N * H_N);
    } else {
        float* keys   = (float*)d_ws;
        float* scores = keys + (long long)B_N * LQ_N * H_N;

        gemm_k<false, true, false><<<dim3(H_N / BN, (B_N * LQ_N) / BM, 1), 256, 0, stream>>>(
            q, W, bias, keys, B_N * LQ_N, H_N, H_N, 0, 0, 0);
        gemm_k<true, false, false><<<dim3(LQ_N / BN, LP_N / BM, B_N), 256, 0, stream>>>(
            p, keys, nullptr, scores, LP_N, LQ_N, H_N,
            (long long)LP_N * H_N, (long long)LQ_N * H_N, (long long)LP_N * LQ_N);
        softmax_k<<<B_N * LP_N, 256, 0, stream>>>(scores);
        gemm_k<false, false, true><<<dim3(H_N / BN, LP_N / BM, B_N), 256, 0, stream>>>(
            scores, q, nullptr, out, LP_N, H_N, LQ_N,
            (long long)LP_N * LQ_N, (long long)LQ_N * H_N, (long long)LP_N * H_N);
    }
}

// Round 17
// 251.250 us; speedup vs baseline: 1.2346x; 1.2346x over previous
//
#include <hip/hip_runtime.h>
#include <hip/hip_bf16.h>

#define B_N 16
#define LP_N 1024
#define LQ_N 1024
#define H_N 1024

typedef unsigned short u16;
typedef __attribute__((ext_vector_type(8))) _Float16 f16x8;
typedef __attribute__((ext_vector_type(4))) float f32x4;

__device__ __forceinline__ u16 f2h(float x) {
    _Float16 h = (_Float16)x;
    return *(u16*)&h;
}
__device__ __forceinline__ float h2f(u16 u) {
    _Float16 h;
    *(u16*)&h = u;
    return (float)h;
}

__device__ __forceinline__ void load_lds16(const u16* g, u16* l) {
    __builtin_amdgcn_global_load_lds(
        (const __attribute__((address_space(1))) void*)g,
        (__attribute__((address_space(3))) void*)l, 16, 0, 0);
}

#define MFMA_F16(a, b, c) __builtin_amdgcn_mfma_f32_16x16x32_f16(a, b, c, 0, 0, 0)
#define VMW0()   asm volatile("s_waitcnt vmcnt(0)" ::: "memory")
#define LGKM12() asm volatile("s_waitcnt lgkmcnt(12)" ::: "memory")
#define LGKM8()  asm volatile("s_waitcnt lgkmcnt(8)" ::: "memory")
#define LGKM0()  asm volatile("s_waitcnt lgkmcnt(0)" ::: "memory")
#define SCHB()   __builtin_amdgcn_sched_barrier(0)
#define SBAR()   __builtin_amdgcn_s_barrier()

// ---------------------------------------------------------------------------
// 256x256 fp16 MFMA GEMM, NT form (R17).
// Model (R13-R16 counters): GEMM time ~ staged_bytes / achieved_staging_BW.
// GEMM1 stages 384MB @5.6 TB/s (ceiling); dense 256MB @3.8 (1 blk/CU);
// R14 showed 2 blk/CU lifts achieved BW to ~5.5. R17: GEMM2 goes SPLIT-K x2
// (grid 512, each block K=512, BK32 dense, LDS 64KB, VGPR<=128 -> 2 blk/CU,
// 16 waves/CU) writing fp32 partials; reduction fused into softmax (adds the
// two partials - same arithmetic modulo one fp32 association). Consecutive
// swizzled blocks = the (kh0,kh1) pair of one tile -> same XCD L2 panels.
// GEMM1 (at BW ceiling) and GEMM3 (reduction pass would cost ~30us > save)
// unchanged from R15 (BK32 split / BK64 dense).
// Numerics (R13-verified, absmax 0.0742):
//   GEMM1: keys = (q_hi + q_lo) @ W_f16  [BK32 split]
//   GEMM2: scores = p @ keys^T           [BK32 dense, split-K x2]
//   GEMM3: out = relu(attn @ qT)         [BK64 dense]
// Swizzle: BK32 slot^=(row>>1)&3; BK64 slot^=row&7; both on pre-swizzled
// global source AND frag ds_read offsets (rule #21; R13/R15-verified 0-conf).
// EPI: 0=fp32 store, 1=+bias fp16 store, 2=relu fp32 store.
// ---------------------------------------------------------------------------
template<int BKT, bool SPLIT, int EPI, bool SK>
__launch_bounds__(512, 2)
__global__ void gemm2t(const u16* __restrict__ Ahi, const u16* __restrict__ Alo,
                       const u16* __restrict__ Bm,
                       const float* __restrict__ bias,
                       float* __restrict__ Cf, u16* __restrict__ Ch,
                       int N, int gn, int gmn,
                       long long sA, long long sB, long long sC, long long sK)
{
    constexpr int REG   = 256 * BKT;             // u16 per 256 x BKT region
    constexpr int O_AL  = REG;                   // split only
    constexpr int O_B   = SPLIT ? 2 * REG : REG;
    constexpr int BUF   = O_B + REG;
    constexpr int NSUBK = BKT / 32;              // 1 (BK32) / 2 (BK64)
    constexpr int CH    = BKT / 16;              // staging chunks/thread/region
    constexpr int RSTEP = 256 / CH;              // row step between chunks
    __shared__ __align__(16) u16 lds[2 * BUF];

    const int tid  = threadIdx.x;
    const int lane = tid & 63;
    const int wv   = tid >> 6;
    const int wr   = wv >> 2, wc = wv & 3;       // 2M x 4N waves

    // XCD-contiguous block swizzle; for SK, consecutive swz = kh pair.
    const int d   = blockIdx.x;
    const int cpx = gridDim.x >> 3;
    const int swz = (d & 7) * cpx + (d >> 3);
    int sw2 = swz, sk = 0;
    if constexpr (SK) { sk = swz & 1; sw2 = swz >> 1; }
    const long long z = sw2 / gmn;
    const int r_  = sw2 % gmn;
    const int bm  = (r_ / gn) * 256;
    const int bn  = (r_ % gn) * 256;

    const char* pAh = (const char*)(Ahi + z * sA) + sk * 1024;  // +512 cols
    const char* pAl = (const char*)(Alo + z * sA) + sk * 1024;
    const char* pB  = (const char*)(Bm + z * sB) + sk * 1024;

    // ---- staging geometry. BK32: rr=tid>>2 (0..127), 4 slots,
    // xor=(rr>>1)&3. BK64: rr=tid>>3 (0..63), 8 slots, xor=rr&7.
    const int rr  = (BKT == 32) ? (tid >> 2) : (tid >> 3);
    const int xcv = (BKT == 32) ? ((tid & 3) ^ ((rr >> 1) & 3))
                                : ((tid & 7) ^ (rr & 7));
    long long aofs[CH], bofs[CH];
#pragma unroll
    for (int j = 0; j < CH; ++j) {
        aofs[j] = (long long)(bm + rr + j * RSTEP) * 2048 + xcv * 16;
        bofs[j] = (long long)(bn + rr + j * RSTEP) * 2048 + xcv * 16;
    }

    // ---- fragment ds_read offsets (u16 units within region)
    int offA[8][NSUBK], offB[4][NSUBK];
#pragma unroll
    for (int i = 0; i < 8; ++i) {
        const int r = wr * 128 + i * 16 + (lane & 15);
#pragma unroll
        for (int s = 0; s < NSUBK; ++s) {
            if constexpr (BKT == 32)
                offA[i][s] = r * 32 + ((((lane >> 4) ^ (r >> 1)) & 3) << 3);
            else
                offA[i][s] = r * 64 + ((((s * 4 + (lane >> 4)) ^ r) & 7) << 3);
        }
    }
#pragma unroll
    for (int j = 0; j < 4; ++j) {
        const int r = wc * 64 + j * 16 + (lane & 15);
#pragma unroll
        for (int s = 0; s < NSUBK; ++s) {
            if constexpr (BKT == 32)
                offB[j][s] = r * 32 + ((((lane >> 4) ^ (r >> 1)) & 3) << 3);
            else
                offB[j][s] = r * 64 + ((((s * 4 + (lane >> 4)) ^ r) & 7) << 3);
        }
    }

    f32x4 acc[8][4];
#pragma unroll
    for (int i = 0; i < 8; ++i)
#pragma unroll
        for (int j = 0; j < 4; ++j)
            acc[i][j] = (f32x4){0.f, 0.f, 0.f, 0.f};

#define STG(NB, KB) do {                                                      \
        _Pragma("unroll")                                                     \
        for (int j = 0; j < CH; ++j) {                                        \
            load_lds16((const u16*)(pAh + aofs[j] + (KB)),                    \
                       lds + (NB) + tid * 8 + j * 4096);                      \
            load_lds16((const u16*)(pB + bofs[j] + (KB)),                     \
                       lds + (NB) + O_B + tid * 8 + j * 4096);                \
            if constexpr (SPLIT)                                              \
                load_lds16((const u16*)(pAl + aofs[j] + (KB)),                \
                           lds + (NB) + O_AL + tid * 8 + j * 4096);           \
        }                                                                     \
    } while (0)

#define TERM(AF, BF) do {                                                     \
        __builtin_amdgcn_s_setprio(1);                                        \
        _Pragma("unroll")                                                     \
        for (int i = 0; i < 8; ++i)                                           \
            _Pragma("unroll")                                                 \
            for (int j = 0; j < 4; ++j)                                       \
                acc[i][j] = MFMA_F16(AF[i], BF[j], acc[i][j]);                \
        __builtin_amdgcn_s_setprio(0);                                        \
    } while (0)

    constexpr int NT = (SK ? 512 : 1024) / BKT;

    STG(0, 0);                                   // prologue: tile 0 -> buf 0

    for (int t = 0; t < NT; ++t) {
        const int cb = (t & 1) ? BUF : 0;
        const int nb = (t & 1) ? 0 : BUF;
        const long long kb = (long long)(t + 1) * (BKT * 2);  // bytes

        VMW0();                  // tile t staged loads retired (per wave)
        SBAR();                  // cross-wave publish

        if constexpr (BKT == 32) {
            f16x8 b[4], ah[8], al[8];
#pragma unroll
            for (int j = 0; j < 4; ++j)
                b[j] = *(const f16x8*)(lds + cb + O_B + offB[j][0]);
#pragma unroll
            for (int i = 0; i < 8; ++i)
                ah[i] = *(const f16x8*)(lds + cb + offA[i][0]);
            if constexpr (SPLIT) {
#pragma unroll
                for (int i = 0; i < 8; ++i)
                    al[i] = *(const f16x8*)(lds + cb + O_AL + offA[i][0]);
            }
            if (t + 1 < NT) STG(nb, kb);
            if constexpr (SPLIT) { LGKM8(); } else { LGKM0(); }
            SCHB();
            TERM(ah, b);
            if constexpr (SPLIT) {
                LGKM0(); SCHB();
                TERM(al, b);
            }
        } else {
            // BK64 dense: subk0 reads, STG, subk1 reads; counted lgkm waits.
            f16x8 b0[4], a0[8], b1[4], a1[8];
#pragma unroll
            for (int j = 0; j < 4; ++j)
                b0[j] = *(const f16x8*)(lds + cb + O_B + offB[j][0]);
#pragma unroll
            for (int i = 0; i < 8; ++i)
                a0[i] = *(const f16x8*)(lds + cb + offA[i][0]);
            if (t + 1 < NT) STG(nb, kb);
#pragma unroll
            for (int j = 0; j < 4; ++j)
                b1[j] = *(const f16x8*)(lds + cb + O_B + offB[j][1]);
#pragma unroll
            for (int i = 0; i < 8; ++i)
                a1[i] = *(const f16x8*)(lds + cb + offA[i][1]);
            LGKM12(); SCHB();
            TERM(a0, b0);                        // subk1 reads in flight
            LGKM0(); SCHB();
            TERM(a1, b1);
        }
    }
#undef STG
#undef TERM

    // epilogue; C/D map: col = lane&15, row = (lane>>4)*4 + e  [m89/m91]
    const long long Cbase = z * sC + (long long)sk * sK;
#pragma unroll
    for (int i = 0; i < 8; ++i) {
        const int row0 = bm + wr * 128 + i * 16 + ((lane >> 4) << 2);
#pragma unroll
        for (int j = 0; j < 4; ++j) {
            const int col = bn + wc * 64 + j * 16 + (lane & 15);
#pragma unroll
            for (int e = 0; e < 4; ++e) {
                const float v = acc[i][j][e];
                const long long idx = Cbase + (long long)(row0 + e) * N + col;
                if constexpr (EPI == 0) {
                    Cf[idx] = v;
                } else if constexpr (EPI == 1) {
                    Ch[idx] = f2h(v + bias[col]);
                } else {
                    Cf[idx] = fmaxf(v, 0.f);
                }
            }
        }
    }
}

// fp32 -> fp16 single, 4 elems/thread (p pre-pass)
__global__ void cvt_f16(const float* __restrict__ in, u16* __restrict__ o16,
                        long long n4)
{
    const long long i = (long long)blockIdx.x * 256 + threadIdx.x;
    if (i >= n4) return;
    const float4 v = ((const float4*)in)[i];
    ushort4 h;
    h.x = f2h(v.x); h.y = f2h(v.y); h.z = f2h(v.z); h.w = f2h(v.w);
    ((ushort4*)o16)[i] = h;
}

// fused q pre-pass: q_hi, q_lo (straight, fp16) and qT (transposed, fp16)
__global__ void fuse_cvt_q(const float* __restrict__ q, u16* __restrict__ hi,
                           u16* __restrict__ lo, u16* __restrict__ thi)
{
    __shared__ float t[32][33];
    const long long z = blockIdx.z;
    const long long base = z * 1048576;
    const int r0 = blockIdx.y * 32, c0 = blockIdx.x * 32;
    for (int j = threadIdx.y; j < 32; j += 8) {
        const float v = q[base + (long long)(r0 + j) * 1024 + c0 + threadIdx.x];
        t[j][threadIdx.x] = v;
        const long long o = base + (long long)(r0 + j) * 1024 + c0 + threadIdx.x;
        const u16 h = f2h(v);
        hi[o] = h;
        lo[o] = f2h(v - h2f(h));
    }
    __syncthreads();
    for (int j = threadIdx.y; j < 32; j += 8)
        thi[base + (long long)(c0 + j) * 1024 + r0 + threadIdx.x] = f2h(t[threadIdx.x][j]);
}

// Wt[c][r] = W[r][c], fp16 single
__global__ void transpose_cvt_w(const float* __restrict__ in, u16* __restrict__ hi)
{
    __shared__ float t[32][33];
    const int r0 = blockIdx.y * 32, c0 = blockIdx.x * 32;
    for (int j = threadIdx.y; j < 32; j += 8)
        t[j][threadIdx.x] = in[(long long)(r0 + j) * 1024 + c0 + threadIdx.x];
    __syncthreads();
    for (int j = threadIdx.y; j < 32; j += 8)
        hi[(long long)(c0 + j) * 1024 + r0 + threadIdx.x] = f2h(t[threadIdx.x][j]);
}

// row softmax over the SUM of two split-K partials (fp32 in x2, fp16 out)
__global__ void softmax2_f16(const float* __restrict__ S0,
                             const float* __restrict__ S1,
                             u16* __restrict__ A)
{
    const long long row = blockIdx.x;
    const int t = threadIdx.x;
    const float4 u0 = ((const float4*)(S0 + row * (long long)LQ_N))[t];
    const float4 u1 = ((const float4*)(S1 + row * (long long)LQ_N))[t];
    float4 v;
    v.x = u0.x + u1.x; v.y = u0.y + u1.y;
    v.z = u0.z + u1.z; v.w = u0.w + u1.w;

    float m = fmaxf(fmaxf(v.x, v.y), fmaxf(v.z, v.w));
#pragma unroll
    for (int off = 32; off > 0; off >>= 1)
        m = fmaxf(m, __shfl_xor(m, off));

    __shared__ float red[4];
    const int lane = t & 63, wid = t >> 6;
    if (lane == 0) red[wid] = m;
    __syncthreads();
    m = fmaxf(fmaxf(red[0], red[1]), fmaxf(red[2], red[3]));
    __syncthreads();

    v.x = __expf(v.x - m); v.y = __expf(v.y - m);
    v.z = __expf(v.z - m); v.w = __expf(v.w - m);
    float s = v.x + v.y + v.z + v.w;
#pragma unroll
    for (int off = 32; off > 0; off >>= 1)
        s += __shfl_xor(s, off);
    if (lane == 0) red[wid] = s;
    __syncthreads();
    s = red[0] + red[1] + red[2] + red[3];

    const float inv = 1.0f / s;
    ushort4 o;
    o.x = f2h(v.x * inv); o.y = f2h(v.y * inv);
    o.z = f2h(v.z * inv); o.w = f2h(v.w * inv);
    ((ushort4*)(A + row * (long long)LQ_N))[t] = o;
}

// ---------------------------------------------------------------------------
// Fallback fp32 path (round-1, verified; needs only 128 MB ws)
// ---------------------------------------------------------------------------
#define BM 128
#define BN 128
#define BK 8
#define TM 8
#define TN 8

template<bool TRANSB, bool BIAS, bool RELU>
__launch_bounds__(256)
__global__ void gemm_k(const float* __restrict__ A, const float* __restrict__ Bmat,
                       const float* __restrict__ bias, float* __restrict__ C,
                       int M, int N, int K,
                       long long sA, long long sB, long long sC)
{
    __shared__ float As[BK][BM];
    __shared__ float Bs[BK][BN];
    const int tid = threadIdx.x;
    const int tx = tid & 15;
    const int ty = tid >> 4;
    const int bn = blockIdx.x * BN;
    const int bm = blockIdx.y * BM;
    const long long z = blockIdx.z;
    A += z * sA; Bmat += z * sB; C += z * sC;
    float acc[TM][TN];
#pragma unroll
    for (int i = 0; i < TM; i++)
#pragma unroll
        for (int j = 0; j < TN; j++) acc[i][j] = 0.f;
    const int arow = tid >> 1;
    const int acol = (tid & 1) * 4;
    const int bk_n = tid >> 5;
    const int bn_n = (tid & 31) * 4;
    for (int k0 = 0; k0 < K; k0 += BK) {
        float4 a4 = *(const float4*)&A[(long long)(bm + arow) * K + k0 + acol];
        As[acol + 0][arow] = a4.x; As[acol + 1][arow] = a4.y;
        As[acol + 2][arow] = a4.z; As[acol + 3][arow] = a4.w;
        if (TRANSB) {
            float4 b4 = *(const float4*)&Bmat[(long long)(bn + arow) * K + k0 + acol];
            Bs[acol + 0][arow] = b4.x; Bs[acol + 1][arow] = b4.y;
            Bs[acol + 2][arow] = b4.z; Bs[acol + 3][arow] = b4.w;
        } else {
            float4 b4 = *(const float4*)&Bmat[(long long)(k0 + bk_n) * N + bn + bn_n];
            *(float4*)&Bs[bk_n][bn_n] = b4;
        }
        __syncthreads();
#pragma unroll
        for (int k = 0; k < BK; k++) {
            float a[TM], b[TN];
            *(float4*)&a[0] = *(const float4*)&As[k][ty * TM];
            *(float4*)&a[4] = *(const float4*)&As[k][ty * TM + 4];
            *(float4*)&b[0] = *(const float4*)&Bs[k][tx * TN];
            *(float4*)&b[4] = *(const float4*)&Bs[k][tx * TN + 4];
#pragma unroll
            for (int i = 0; i < TM; i++)
#pragma unroll
                for (int j = 0; j < TN; j++)
                    acc[i][j] = fmaf(a[i], b[j], acc[i][j]);
        }
        __syncthreads();
    }
#pragma unroll
    for (int i = 0; i < TM; i++) {
        const int row = bm + ty * TM + i;
#pragma unroll
        for (int j = 0; j < TN; j += 4) {
            const int col = bn + tx * TN + j;
            float4 v;
            v.x = acc[i][j + 0]; v.y = acc[i][j + 1];
            v.z = acc[i][j + 2]; v.w = acc[i][j + 3];
            if (BIAS) {
                v.x += bias[col + 0]; v.y += bias[col + 1];
                v.z += bias[col + 2]; v.w += bias[col + 3];
            }
            if (RELU) {
                v.x = fmaxf(v.x, 0.f); v.y = fmaxf(v.y, 0.f);
                v.z = fmaxf(v.z, 0.f); v.w = fmaxf(v.w, 0.f);
            }
            *(float4*)&C[(long long)row * N + col] = v;
        }
    }
}

__global__ void softmax_k(float* __restrict__ S)
{
    const long long row = blockIdx.x;
    float* r = S + row * (long long)LQ_N;
    const int t = threadIdx.x;
    float4 v = ((float4*)r)[t];
    float m = fmaxf(fmaxf(v.x, v.y), fmaxf(v.z, v.w));
#pragma unroll
    for (int off = 32; off > 0; off >>= 1)
        m = fmaxf(m, __shfl_xor(m, off));
    __shared__ float red[4];
    const int lane = t & 63, wid = t >> 6;
    if (lane == 0) red[wid] = m;
    __syncthreads();
    m = fmaxf(fmaxf(red[0], red[1]), fmaxf(red[2], red[3]));
    __syncthreads();
    v.x = __expf(v.x - m); v.y = __expf(v.y - m);
    v.z = __expf(v.z - m); v.w = __expf(v.w - m);
    float s = v.x + v.y + v.z + v.w;
#pragma unroll
    for (int off = 32; off > 0; off >>= 1)
        s += __shfl_xor(s, off);
    if (lane == 0) red[wid] = s;
    __syncthreads();
    s = red[0] + red[1] + red[2] + red[3];
    const float inv = 1.0f / s;
    v.x *= inv; v.y *= inv; v.z *= inv; v.w *= inv;
    ((float4*)r)[t] = v;
}

extern "C" void kernel_launch(void* const* d_in, const int* in_sizes, int n_in,
                              void* d_out, int out_size, void* d_ws, size_t ws_size,
                              hipStream_t stream)
{
    const float* p    = (const float*)d_in[0];
    const float* q    = (const float*)d_in[1];
    const float* W    = (const float*)d_in[2];
    const float* bias = (const float*)d_in[3];
    float* out = (float*)d_out;

    const size_t MB32 = 33554432ull;                        // 32 MB unit
    const size_t NEED = 5 * MB32 + 2097152ull + 2 * MB32;   // 226 MB

    if (ws_size >= NEED) {
        char* w = (char*)d_ws;
        u16* p16   = (u16*)(w + 0 * MB32);
        u16* q_hi  = (u16*)(w + 1 * MB32);
        u16* q_lo  = (u16*)(w + 2 * MB32);
        u16* keys  = (u16*)(w + 3 * MB32);
        u16* qT    = (u16*)(w + 4 * MB32);
        u16* Wt    = (u16*)(w + 5 * MB32);
        float* s0  = (float*)(w + 1 * MB32);                // reuses q_hi/q_lo
        float* s1  = (float*)(w + 5 * MB32 + 2097152ull);   // after Wt
        u16* attn  = (u16*)(w + 0 * MB32);                  // reuses p16

        const long long n4 = (long long)B_N * LQ_N * H_N / 4;
        cvt_f16<<<dim3((unsigned)(n4 / 256)), 256, 0, stream>>>(p, p16, n4);
        fuse_cvt_q<<<dim3(32, 32, B_N), dim3(32, 8), 0, stream>>>(q, q_hi, q_lo, qT);
        transpose_cvt_w<<<dim3(32, 32, 1), dim3(32, 8), 0, stream>>>(W, Wt);

        // keys = (q_hi + q_lo) @ Wt + b : BK32 split, grid 256 (R15 config).
        gemm2t<32, true, 1, false><<<256, 512, 0, stream>>>(
            q_hi, q_lo, Wt, bias, nullptr, keys,
            H_N, /*gn=*/4, /*gmn=*/256, 0, 0, 0, 0);

        // scores partials: split-K x2, BK32 dense, grid 512 (2 blk/CU).
        gemm2t<32, false, 0, true><<<512, 512, 0, stream>>>(
            p16, p16, keys, nullptr, s0, nullptr,
            LQ_N, /*gn=*/4, /*gmn=*/16,
            (long long)LP_N * H_N, (long long)LQ_N * H_N, (long long)LP_N * LQ_N,
            /*sK=*/(long long)(s1 - s0));

        // softmax over s0+s1, fp16 attn out.
        softmax2_f16<<<B_N * LP_N, 256, 0, stream>>>(s0, s1, attn);

        // out[b] = relu(attn[b] @ q[b]) : BK64 dense, grid 256 (R15 config).
        gemm2t<64, false, 2, false><<<256, 512, 0, stream>>>(
            attn, attn, qT, nullptr, out, nullptr,
            H_N, /*gn=*/4, /*gmn=*/16,
            (long long)LP_N * LQ_N, (long long)H_N * LQ_N, (long long)LP_N * H_N, 0);
    } else {
        float* keys   = (float*)d_ws;
        float* scores = keys + (long long)B_N * LQ_N * H_N;

        gemm_k<false, true, false><<<dim3(H_N / BN, (B_N * LQ_N) / BM, 1), 256, 0, stream>>>(
            q, W, bias, keys, B_N * LQ_N, H_N, H_N, 0, 0, 0);
        gemm_k<true, false, false><<<dim3(LQ_N / BN, LP_N / BM, B_N), 256, 0, stream>>>(
            p, keys, nullptr, scores, LP_N, LQ_N, H_N,
            (long long)LP_N * H_N, (long long)LQ_N * H_N, (long long)LP_N * LQ_N);
        softmax_k<<<B_N * LP_N, 256, 0, stream>>>(scores);
        gemm_k<false, false, true><<<dim3(H_N / BN, LP_N / BM, B_N), 256, 0, stream>>>(
            scores, q, nullptr, out, LP_N, H_N, LQ_N,
            (long long)LP_N * LQ_N, (long long)LQ_N * H_N, (long long)LP_N * H_N);
    }
}

// Round 18
// 229.646 us; speedup vs baseline: 1.3508x; 1.0941x over previous
//
#include <hip/hip_runtime.h>
#include <hip/hip_bf16.h>

#define B_N 16
#define LP_N 1024
#define LQ_N 1024
#define H_N 1024

typedef unsigned short u16;
typedef __attribute__((ext_vector_type(8))) _Float16 f16x8;
typedef __attribute__((ext_vector_type(4))) float f32x4;

__device__ __forceinline__ u16 f2h(float x) {
    _Float16 h = (_Float16)x;
    return *(u16*)&h;
}
__device__ __forceinline__ float h2f(u16 u) {
    _Float16 h;
    *(u16*)&h = u;
    return (float)h;
}

__device__ __forceinline__ void load_lds16(const u16* g, u16* l) {
    __builtin_amdgcn_global_load_lds(
        (const __attribute__((address_space(1))) void*)g,
        (__attribute__((address_space(3))) void*)l, 16, 0, 0);
}

#define MFMA_F16(a, b, c) __builtin_amdgcn_mfma_f32_16x16x32_f16(a, b, c, 0, 0, 0)
#define VMW0()  asm volatile("s_waitcnt vmcnt(0)" ::: "memory")
#define VMW4()  asm volatile("s_waitcnt vmcnt(4)" ::: "memory")
#define LGKM8() asm volatile("s_waitcnt lgkmcnt(8)" ::: "memory")
#define LGKM0() asm volatile("s_waitcnt lgkmcnt(0)" ::: "memory")
#define SCHB()  __builtin_amdgcn_sched_barrier(0)
#define SBAR()  __builtin_amdgcn_s_barrier()

// ---------------------------------------------------------------------------
// GEMM1 (R15-verified, unchanged): 256x256 fp16 split, BK=32, dbuf, per-tile
// vmcnt(0)+s_barrier gate. Stages 384MB @5.6 TB/s (at staging ceiling).
// ---------------------------------------------------------------------------
template<bool SPLIT, int EPI>
__launch_bounds__(512, 2)
__global__ void gemm2t(const u16* __restrict__ Ahi, const u16* __restrict__ Alo,
                       const u16* __restrict__ Bm,
                       const float* __restrict__ bias,
                       float* __restrict__ Cf, u16* __restrict__ Ch,
                       int N, int gn, int gmn,
                       long long sA, long long sB, long long sC)
{
    constexpr int REG  = 8192;
    constexpr int O_AL = REG;
    constexpr int O_B  = SPLIT ? 2 * REG : REG;
    constexpr int BUF  = SPLIT ? 3 * REG : 2 * REG;
    __shared__ __align__(16) u16 lds[2 * BUF];

    const int tid  = threadIdx.x;
    const int lane = tid & 63;
    const int wv   = tid >> 6;
    const int wr   = wv >> 2, wc = wv & 3;

    const int d   = blockIdx.x;
    const int cpx = gridDim.x >> 3;
    const int swz = (d & 7) * cpx + (d >> 3);
    const long long z = swz / gmn;
    const int r_  = swz % gmn;
    const int bm  = (r_ / gn) * 256;
    const int bn  = (r_ % gn) * 256;

    const char* pAh = (const char*)(Ahi + z * sA);
    const char* pAl = (const char*)(Alo + z * sA);
    const char* pB  = (const char*)(Bm + z * sB);

    const int r0 = tid >> 2;
    const int xc = (tid & 3) ^ ((r0 >> 1) & 3);
    const long long aof = (long long)(bm + r0) * 2048 + xc * 16;
    const long long bof = (long long)(bn + r0) * 2048 + xc * 16;
    const long long ao2 = aof + 128 * 2048;
    const long long bo2 = bof + 128 * 2048;
    const int d0 = tid * 8;
    const int d1 = d0 + 4096;

    int offA[8], offB[4];
#pragma unroll
    for (int i = 0; i < 8; ++i) {
        const int r = wr * 128 + i * 16 + (lane & 15);
        offA[i] = r * 32 + ((((lane >> 4) ^ (r >> 1)) & 3) << 3);
    }
#pragma unroll
    for (int j = 0; j < 4; ++j) {
        const int r = wc * 64 + j * 16 + (lane & 15);
        offB[j] = r * 32 + ((((lane >> 4) ^ (r >> 1)) & 3) << 3);
    }

    f32x4 acc[8][4];
#pragma unroll
    for (int i = 0; i < 8; ++i)
#pragma unroll
        for (int j = 0; j < 4; ++j)
            acc[i][j] = (f32x4){0.f, 0.f, 0.f, 0.f};

#define STG(NB, KB) do {                                                      \
        load_lds16((const u16*)(pAh + aof + (KB)), lds + (NB) + d0);          \
        load_lds16((const u16*)(pAh + ao2 + (KB)), lds + (NB) + d1);          \
        load_lds16((const u16*)(pB + bof + (KB)), lds + (NB) + O_B + d0);     \
        load_lds16((const u16*)(pB + bo2 + (KB)), lds + (NB) + O_B + d1);     \
        if constexpr (SPLIT) {                                                \
            load_lds16((const u16*)(pAl + aof + (KB)), lds + (NB) + O_AL + d0); \
            load_lds16((const u16*)(pAl + ao2 + (KB)), lds + (NB) + O_AL + d1); \
        }                                                                     \
    } while (0)

#define TERM(AF, BF) do {                                                     \
        __builtin_amdgcn_s_setprio(1);                                        \
        _Pragma("unroll")                                                     \
        for (int i = 0; i < 8; ++i)                                           \
            _Pragma("unroll")                                                 \
            for (int j = 0; j < 4; ++j)                                       \
                acc[i][j] = MFMA_F16(AF[i], BF[j], acc[i][j]);                \
        __builtin_amdgcn_s_setprio(0);                                        \
    } while (0)

    constexpr int NT = 32;

    STG(0, 0);

    for (int t = 0; t < NT; ++t) {
        const int cb = (t & 1) ? BUF : 0;
        const int nb = (t & 1) ? 0 : BUF;
        const long long kb = (long long)(t + 1) * 64;

        VMW0();
        SBAR();
        f16x8 b[4], ah[8], al[8];
#pragma unroll
        for (int j = 0; j < 4; ++j)
            b[j] = *(const f16x8*)(lds + cb + O_B + offB[j]);
#pragma unroll
        for (int i = 0; i < 8; ++i)
            ah[i] = *(const f16x8*)(lds + cb + offA[i]);
        if constexpr (SPLIT) {
#pragma unroll
            for (int i = 0; i < 8; ++i)
                al[i] = *(const f16x8*)(lds + cb + O_AL + offA[i]);
        }
        if (t + 1 < NT) STG(nb, kb);
        if constexpr (SPLIT) { LGKM8(); } else { LGKM0(); }
        SCHB();
        TERM(ah, b);
        if constexpr (SPLIT) {
            LGKM0(); SCHB();
            TERM(al, b);
        }
    }
#undef STG
#undef TERM

    const long long Cbase = z * sC;
#pragma unroll
    for (int i = 0; i < 8; ++i) {
        const int row0 = bm + wr * 128 + i * 16 + ((lane >> 4) << 2);
#pragma unroll
        for (int j = 0; j < 4; ++j) {
            const int col = bn + wc * 64 + j * 16 + (lane & 15);
#pragma unroll
            for (int e = 0; e < 4; ++e) {
                const float v = acc[i][j][e];
                const long long idx = Cbase + (long long)(row0 + e) * N + col;
                if constexpr (EPI == 0) {
                    Cf[idx] = v;
                } else if constexpr (EPI == 1) {
                    Ch[idx] = f2h(v + bias[col]);
                } else {
                    Cf[idx] = fmaxf(v, 0.f);
                }
            }
        }
    }
}

// ---------------------------------------------------------------------------
// R18 dense GEMM: BK=32, TRIPLE-buffered, DEPTH-2 prefetch with counted
// vmcnt. Per tile t: wait vmcnt(4) (retires exactly tile t's 4 staging
// loads; tile t+1's 4 stay in flight - never drains to 0 until the last
// tile), s_barrier, read frags from buf t%3, stage tile t+2 -> buf (t+2)%3,
// lgkmcnt(0)+sched_barrier, 32 MFMA. Loads get ~2 tiles of latency slack
// instead of 1 (the R13-R16 counters show dense achieved staging BW 3.8
// TB/s vs GEMM1's 5.6 at higher in-flight count -> staging MLP hypothesis).
// Race-check: buf (t+2)%3 was last READ at tile t-1, whose lgkmcnt(0)
// completed before this tile's s_barrier -> write-after-read safe.
// Swizzle + numerics identical to R13/R15 (verified 0-conflict, 0.0742).
// EPI: 0 = fp32 store, 2 = relu fp32 store.
// ---------------------------------------------------------------------------
template<int EPI>
__launch_bounds__(512, 2)
__global__ void gemm_d2(const u16* __restrict__ Am, const u16* __restrict__ Bm,
                        float* __restrict__ Cf,
                        int N, int gn, int gmn,
                        long long sA, long long sB, long long sC)
{
    constexpr int REG = 8192;                    // u16 per 256x32 region
    constexpr int O_B = REG;
    constexpr int BUF = 2 * REG;                 // 32KB per buffer
    __shared__ __align__(16) u16 lds[3 * BUF];   // 96KB triple buffer

    const int tid  = threadIdx.x;
    const int lane = tid & 63;
    const int wv   = tid >> 6;
    const int wr   = wv >> 2, wc = wv & 3;

    const int d   = blockIdx.x;
    const int cpx = gridDim.x >> 3;
    const int swz = (d & 7) * cpx + (d >> 3);
    const long long z = swz / gmn;
    const int r_  = swz % gmn;
    const int bm  = (r_ / gn) * 256;
    const int bn  = (r_ % gn) * 256;

    const char* pA = (const char*)(Am + z * sA);
    const char* pB = (const char*)(Bm + z * sB);

    const int r0 = tid >> 2;
    const int xc = (tid & 3) ^ ((r0 >> 1) & 3);
    const long long aof = (long long)(bm + r0) * 2048 + xc * 16;
    const long long bof = (long long)(bn + r0) * 2048 + xc * 16;
    const long long ao2 = aof + 128 * 2048;
    const long long bo2 = bof + 128 * 2048;
    const int d0 = tid * 8;
    const int d1 = d0 + 4096;

    int offA[8], offB[4];
#pragma unroll
    for (int i = 0; i < 8; ++i) {
        const int r = wr * 128 + i * 16 + (lane & 15);
        offA[i] = r * 32 + ((((lane >> 4) ^ (r >> 1)) & 3) << 3);
    }
#pragma unroll
    for (int j = 0; j < 4; ++j) {
        const int r = wc * 64 + j * 16 + (lane & 15);
        offB[j] = r * 32 + ((((lane >> 4) ^ (r >> 1)) & 3) << 3);
    }

    f32x4 acc[8][4];
#pragma unroll
    for (int i = 0; i < 8; ++i)
#pragma unroll
        for (int j = 0; j < 4; ++j)
            acc[i][j] = (f32x4){0.f, 0.f, 0.f, 0.f};

#define STG(NB, KB) do {                                                      \
        load_lds16((const u16*)(pA + aof + (KB)), lds + (NB) + d0);           \
        load_lds16((const u16*)(pA + ao2 + (KB)), lds + (NB) + d1);           \
        load_lds16((const u16*)(pB + bof + (KB)), lds + (NB) + O_B + d0);     \
        load_lds16((const u16*)(pB + bo2 + (KB)), lds + (NB) + O_B + d1);     \
    } while (0)

#define TERM(AF, BF) do {                                                     \
        __builtin_amdgcn_s_setprio(1);                                        \
        _Pragma("unroll")                                                     \
        for (int i = 0; i < 8; ++i)                                           \
            _Pragma("unroll")                                                 \
            for (int j = 0; j < 4; ++j)                                       \
                acc[i][j] = MFMA_F16(AF[i], BF[j], acc[i][j]);                \
        __builtin_amdgcn_s_setprio(0);                                        \
    } while (0)

    constexpr int NT = 32;

    // prologue: stage tiles 0, 1 (depth 2)
    STG(0, 0);
    STG(BUF, 64);

    int cb = 0;                                  // buffer offset of tile t
    for (int t = 0; t < NT; ++t) {
        // retire exactly tile t's 4 loads; keep t+1's in flight (counted)
        if (t + 1 < NT) { VMW4(); } else { VMW0(); }
        SBAR();
        f16x8 b[4], a[8];
#pragma unroll
        for (int j = 0; j < 4; ++j)
            b[j] = *(const f16x8*)(lds + cb + O_B + offB[j]);
#pragma unroll
        for (int i = 0; i < 8; ++i)
            a[i] = *(const f16x8*)(lds + cb + offA[i]);
        if (t + 2 < NT) {
            const int nb = (cb + 2 * BUF) % (3 * BUF);   // buf (t+2)%3
            STG(nb, (long long)(t + 2) * 64);
        }
        LGKM0(); SCHB();
        TERM(a, b);
        cb += BUF;
        if (cb == 3 * BUF) cb = 0;
    }
#undef STG
#undef TERM

    const long long Cbase = z * sC;
#pragma unroll
    for (int i = 0; i < 8; ++i) {
        const int row0 = bm + wr * 128 + i * 16 + ((lane >> 4) << 2);
#pragma unroll
        for (int j = 0; j < 4; ++j) {
            const int col = bn + wc * 64 + j * 16 + (lane & 15);
#pragma unroll
            for (int e = 0; e < 4; ++e) {
                const float v = acc[i][j][e];
                const long long idx = Cbase + (long long)(row0 + e) * N + col;
                if constexpr (EPI == 0) Cf[idx] = v;
                else                    Cf[idx] = fmaxf(v, 0.f);
            }
        }
    }
}

// fp32 -> fp16 single, 4 elems/thread (p pre-pass)
__global__ void cvt_f16(const float* __restrict__ in, u16* __restrict__ o16,
                        long long n4)
{
    const long long i = (long long)blockIdx.x * 256 + threadIdx.x;
    if (i >= n4) return;
    const float4 v = ((const float4*)in)[i];
    ushort4 h;
    h.x = f2h(v.x); h.y = f2h(v.y); h.z = f2h(v.z); h.w = f2h(v.w);
    ((ushort4*)o16)[i] = h;
}

// fused q pre-pass: q_hi, q_lo (straight, fp16) and qT (transposed, fp16)
__global__ void fuse_cvt_q(const float* __restrict__ q, u16* __restrict__ hi,
                           u16* __restrict__ lo, u16* __restrict__ thi)
{
    __shared__ float t[32][33];
    const long long z = blockIdx.z;
    const long long base = z * 1048576;
    const int r0 = blockIdx.y * 32, c0 = blockIdx.x * 32;
    for (int j = threadIdx.y; j < 32; j += 8) {
        const float v = q[base + (long long)(r0 + j) * 1024 + c0 + threadIdx.x];
        t[j][threadIdx.x] = v;
        const long long o = base + (long long)(r0 + j) * 1024 + c0 + threadIdx.x;
        const u16 h = f2h(v);
        hi[o] = h;
        lo[o] = f2h(v - h2f(h));
    }
    __syncthreads();
    for (int j = threadIdx.y; j < 32; j += 8)
        thi[base + (long long)(c0 + j) * 1024 + r0 + threadIdx.x] = f2h(t[threadIdx.x][j]);
}

// Wt[c][r] = W[r][c], fp16 single
__global__ void transpose_cvt_w(const float* __restrict__ in, u16* __restrict__ hi)
{
    __shared__ float t[32][33];
    const int r0 = blockIdx.y * 32, c0 = blockIdx.x * 32;
    for (int j = threadIdx.y; j < 32; j += 8)
        t[j][threadIdx.x] = in[(long long)(r0 + j) * 1024 + c0 + threadIdx.x];
    __syncthreads();
    for (int j = threadIdx.y; j < 32; j += 8)
        hi[(long long)(c0 + j) * 1024 + r0 + threadIdx.x] = f2h(t[threadIdx.x][j]);
}

// row softmax (fp32 in, fp16 out)
__global__ void softmax_f16(const float* __restrict__ S, u16* __restrict__ A)
{
    const long long row = blockIdx.x;
    const float* r = S + row * (long long)LQ_N;
    const int t = threadIdx.x;
    float4 v = ((const float4*)r)[t];

    float m = fmaxf(fmaxf(v.x, v.y), fmaxf(v.z, v.w));
#pragma unroll
    for (int off = 32; off > 0; off >>= 1)
        m = fmaxf(m, __shfl_xor(m, off));

    __shared__ float red[4];
    const int lane = t & 63, wid = t >> 6;
    if (lane == 0) red[wid] = m;
    __syncthreads();
    m = fmaxf(fmaxf(red[0], red[1]), fmaxf(red[2], red[3]));
    __syncthreads();

    v.x = __expf(v.x - m); v.y = __expf(v.y - m);
    v.z = __expf(v.z - m); v.w = __expf(v.w - m);
    float s = v.x + v.y + v.z + v.w;
#pragma unroll
    for (int off = 32; off > 0; off >>= 1)
        s += __shfl_xor(s, off);
    if (lane == 0) red[wid] = s;
    __syncthreads();
    s = red[0] + red[1] + red[2] + red[3];

    const float inv = 1.0f / s;
    ushort4 o;
    o.x = f2h(v.x * inv); o.y = f2h(v.y * inv);
    o.z = f2h(v.z * inv); o.w = f2h(v.w * inv);
    ((ushort4*)(A + row * (long long)LQ_N))[t] = o;
}

// ---------------------------------------------------------------------------
// Fallback fp32 path (round-1, verified; needs only 128 MB ws)
// ---------------------------------------------------------------------------
#define BM 128
#define BN 128
#define BK 8
#define TM 8
#define TN 8

template<bool TRANSB, bool BIAS, bool RELU>
__launch_bounds__(256)
__global__ void gemm_k(const float* __restrict__ A, const float* __restrict__ Bmat,
                       const float* __restrict__ bias, float* __restrict__ C,
                       int M, int N, int K,
                       long long sA, long long sB, long long sC)
{
    __shared__ float As[BK][BM];
    __shared__ float Bs[BK][BN];
    const int tid = threadIdx.x;
    const int tx = tid & 15;
    const int ty = tid >> 4;
    const int bn = blockIdx.x * BN;
    const int bm = blockIdx.y * BM;
    const long long z = blockIdx.z;
    A += z * sA; Bmat += z * sB; C += z * sC;
    float acc[TM][TN];
#pragma unroll
    for (int i = 0; i < TM; i++)
#pragma unroll
        for (int j = 0; j < TN; j++) acc[i][j] = 0.f;
    const int arow = tid >> 1;
    const int acol = (tid & 1) * 4;
    const int bk_n = tid >> 5;
    const int bn_n = (tid & 31) * 4;
    for (int k0 = 0; k0 < K; k0 += BK) {
        float4 a4 = *(const float4*)&A[(long long)(bm + arow) * K + k0 + acol];
        As[acol + 0][arow] = a4.x; As[acol + 1][arow] = a4.y;
        As[acol + 2][arow] = a4.z; As[acol + 3][arow] = a4.w;
        if (TRANSB) {
            float4 b4 = *(const float4*)&Bmat[(long long)(bn + arow) * K + k0 + acol];
            Bs[acol + 0][arow] = b4.x; Bs[acol + 1][arow] = b4.y;
            Bs[acol + 2][arow] = b4.z; Bs[acol + 3][arow] = b4.w;
        } else {
            float4 b4 = *(const float4*)&Bmat[(long long)(k0 + bk_n) * N + bn + bn_n];
            *(float4*)&Bs[bk_n][bn_n] = b4;
        }
        __syncthreads();
#pragma unroll
        for (int k = 0; k < BK; k++) {
            float a[TM], b[TN];
            *(float4*)&a[0] = *(const float4*)&As[k][ty * TM];
            *(float4*)&a[4] = *(const float4*)&As[k][ty * TM + 4];
            *(float4*)&b[0] = *(const float4*)&Bs[k][tx * TN];
            *(float4*)&b[4] = *(const float4*)&Bs[k][tx * TN + 4];
#pragma unroll
            for (int i = 0; i < TM; i++)
#pragma unroll
                for (int j = 0; j < TN; j++)
                    acc[i][j] = fmaf(a[i], b[j], acc[i][j]);
        }
        __syncthreads();
    }
#pragma unroll
    for (int i = 0; i < TM; i++) {
        const int row = bm + ty * TM + i;
#pragma unroll
        for (int j = 0; j < TN; j += 4) {
            const int col = bn + tx * TN + j;
            float4 v;
            v.x = acc[i][j + 0]; v.y = acc[i][j + 1];
            v.z = acc[i][j + 2]; v.w = acc[i][j + 3];
            if (BIAS) {
                v.x += bias[col + 0]; v.y += bias[col + 1];
                v.z += bias[col + 2]; v.w += bias[col + 3];
            }
            if (RELU) {
                v.x = fmaxf(v.x, 0.f); v.y = fmaxf(v.y, 0.f);
                v.z = fmaxf(v.z, 0.f); v.w = fmaxf(v.w, 0.f);
            }
            *(float4*)&C[(long long)row * N + col] = v;
        }
    }
}

__global__ void softmax_k(float* __restrict__ S)
{
    const long long row = blockIdx.x;
    float* r = S + row * (long long)LQ_N;
    const int t = threadIdx.x;
    float4 v = ((float4*)r)[t];
    float m = fmaxf(fmaxf(v.x, v.y), fmaxf(v.z, v.w));
#pragma unroll
    for (int off = 32; off > 0; off >>= 1)
        m = fmaxf(m, __shfl_xor(m, off));
    __shared__ float red[4];
    const int lane = t & 63, wid = t >> 6;
    if (lane == 0) red[wid] = m;
    __syncthreads();
    m = fmaxf(fmaxf(red[0], red[1]), fmaxf(red[2], red[3]));
    __syncthreads();
    v.x = __expf(v.x - m); v.y = __expf(v.y - m);
    v.z = __expf(v.z - m); v.w = __expf(v.w - m);
    float s = v.x + v.y + v.z + v.w;
#pragma unroll
    for (int off = 32; off > 0; off >>= 1)
        s += __shfl_xor(s, off);
    if (lane == 0) red[wid] = s;
    __syncthreads();
    s = red[0] + red[1] + red[2] + red[3];
    const float inv = 1.0f / s;
    v.x *= inv; v.y *= inv; v.z *= inv; v.w *= inv;
    ((float4*)r)[t] = v;
}

extern "C" void kernel_launch(void* const* d_in, const int* in_sizes, int n_in,
                              void* d_out, int out_size, void* d_ws, size_t ws_size,
                              hipStream_t stream)
{
    const float* p    = (const float*)d_in[0];
    const float* q    = (const float*)d_in[1];
    const float* W    = (const float*)d_in[2];
    const float* bias = (const float*)d_in[3];
    float* out = (float*)d_out;

    const size_t MB32 = 33554432ull;                 // 32 MB unit
    const size_t NEED = 5 * MB32 + 2097152ull;       // 162 MB

    if (ws_size >= NEED) {
        char* w = (char*)d_ws;
        u16* p16   = (u16*)(w + 0 * MB32);
        u16* q_hi  = (u16*)(w + 1 * MB32);
        u16* q_lo  = (u16*)(w + 2 * MB32);
        u16* keys  = (u16*)(w + 3 * MB32);
        u16* qT    = (u16*)(w + 4 * MB32);
        u16* Wt    = (u16*)(w + 5 * MB32);
        float* scores = (float*)(w + 1 * MB32);  // reuses q_hi/q_lo after GEMM1
        u16* attn     = (u16*)(w + 0 * MB32);    // reuses p16 after GEMM2

        const long long n4 = (long long)B_N * LQ_N * H_N / 4;
        cvt_f16<<<dim3((unsigned)(n4 / 256)), 256, 0, stream>>>(p, p16, n4);
        fuse_cvt_q<<<dim3(32, 32, B_N), dim3(32, 8), 0, stream>>>(q, q_hi, q_lo, qT);
        transpose_cvt_w<<<dim3(32, 32, 1), dim3(32, 8), 0, stream>>>(W, Wt);

        // keys = (q_hi + q_lo) @ Wt + b : BK32 split, grid 256 (R15 config).
        gemm2t<true, 1><<<256, 512, 0, stream>>>(
            q_hi, q_lo, Wt, bias, nullptr, keys,
            H_N, /*gn=*/4, /*gmn=*/256, 0, 0, 0);

        // scores[b] = p16[b] @ keys[b]^T : dense depth-2 triple-buffer.
        gemm_d2<0><<<256, 512, 0, stream>>>(
            p16, keys, scores,
            LQ_N, /*gn=*/4, /*gmn=*/16,
            (long long)LP_N * H_N, (long long)LQ_N * H_N, (long long)LP_N * LQ_N);

        softmax_f16<<<B_N * LP_N, 256, 0, stream>>>(scores, attn);

        // out[b] = relu(attn[b] @ q[b]) : dense depth-2 triple-buffer.
        gemm_d2<2><<<256, 512, 0, stream>>>(
            attn, qT, out,
            H_N, /*gn=*/4, /*gmn=*/16,
            (long long)LP_N * LQ_N, (long long)H_N * LQ_N, (long long)LP_N * H_N);
    } else {
        float* keys   = (float*)d_ws;
        float* scores = keys + (long long)B_N * LQ_N * H_N;

        gemm_k<false, true, false><<<dim3(H_N / BN, (B_N * LQ_N) / BM, 1), 256, 0, stream>>>(
            q, W, bias, keys, B_N * LQ_N, H_N, H_N, 0, 0, 0);
        gemm_k<true, false, false><<<dim3(LQ_N / BN, LP_N / BM, B_N), 256, 0, stream>>>(
            p, keys, nullptr, scores, LP_N, LQ_N, H_N,
            (long long)LP_N * H_N, (long long)LQ_N * H_N, (long long)LP_N * LQ_N);
        softmax_k<<<B_N * LP_N, 256, 0, stream>>>(scores);
        gemm_k<false, false, true><<<dim3(H_N / BN, LP_N / BM, B_N), 256, 0, stream>>>(
            scores, q, nullptr, out, LP_N, H_N, LQ_N,
            (long long)LP_N * LQ_N, (long long)LQ_N * H_N, (long long)LP_N * H_N);
    }
}

// Round 19
// 221.390 us; speedup vs baseline: 1.4011x; 1.0373x over previous
//
#include <hip/hip_runtime.h>
#include <hip/hip_bf16.h>

#define B_N 16
#define LP_N 1024
#define LQ_N 1024
#define H_N 1024

typedef unsigned short u16;
typedef __attribute__((ext_vector_type(8))) _Float16 f16x8;
typedef __attribute__((ext_vector_type(4))) float f32x4;

__device__ __forceinline__ u16 f2h(float x) {
    _Float16 h = (_Float16)x;
    return *(u16*)&h;
}
__device__ __forceinline__ float h2f(u16 u) {
    _Float16 h;
    *(u16*)&h = u;
    return (float)h;
}

__device__ __forceinline__ void load_lds16(const u16* g, u16* l) {
    __builtin_amdgcn_global_load_lds(
        (const __attribute__((address_space(1))) void*)g,
        (__attribute__((address_space(3))) void*)l, 16, 0, 0);
}

#define MFMA_F16(a, b, c) __builtin_amdgcn_mfma_f32_16x16x32_f16(a, b, c, 0, 0, 0)
#define VMW0()  asm volatile("s_waitcnt vmcnt(0)" ::: "memory")
#define VMW4()  asm volatile("s_waitcnt vmcnt(4)" ::: "memory")
#define LGKM8() asm volatile("s_waitcnt lgkmcnt(8)" ::: "memory")
#define LGKM0() asm volatile("s_waitcnt lgkmcnt(0)" ::: "memory")
#define SCHB()  __builtin_amdgcn_sched_barrier(0)
#define SBAR()  __builtin_amdgcn_s_barrier()

// ---------------------------------------------------------------------------
// GEMM1 (R15-verified, unchanged): 256x256 fp16 split, BK=32, dbuf, per-tile
// vmcnt(0)+s_barrier gate. 68us, at this structure's staging ceiling.
// ---------------------------------------------------------------------------
template<bool SPLIT, int EPI>
__launch_bounds__(512, 2)
__global__ void gemm2t(const u16* __restrict__ Ahi, const u16* __restrict__ Alo,
                       const u16* __restrict__ Bm,
                       const float* __restrict__ bias,
                       float* __restrict__ Cf, u16* __restrict__ Ch,
                       int N, int gn, int gmn,
                       long long sA, long long sB, long long sC)
{
    constexpr int REG  = 8192;
    constexpr int O_AL = REG;
    constexpr int O_B  = SPLIT ? 2 * REG : REG;
    constexpr int BUF  = SPLIT ? 3 * REG : 2 * REG;
    __shared__ __align__(16) u16 lds[2 * BUF];

    const int tid  = threadIdx.x;
    const int lane = tid & 63;
    const int wv   = tid >> 6;
    const int wr   = wv >> 2, wc = wv & 3;

    const int d   = blockIdx.x;
    const int cpx = gridDim.x >> 3;
    const int swz = (d & 7) * cpx + (d >> 3);
    const long long z = swz / gmn;
    const int r_  = swz % gmn;
    const int bm  = (r_ / gn) * 256;
    const int bn  = (r_ % gn) * 256;

    const char* pAh = (const char*)(Ahi + z * sA);
    const char* pAl = (const char*)(Alo + z * sA);
    const char* pB  = (const char*)(Bm + z * sB);

    const int r0 = tid >> 2;
    const int xc = (tid & 3) ^ ((r0 >> 1) & 3);
    const long long aof = (long long)(bm + r0) * 2048 + xc * 16;
    const long long bof = (long long)(bn + r0) * 2048 + xc * 16;
    const long long ao2 = aof + 128 * 2048;
    const long long bo2 = bof + 128 * 2048;
    const int d0 = tid * 8;
    const int d1 = d0 + 4096;

    int offA[8], offB[4];
#pragma unroll
    for (int i = 0; i < 8; ++i) {
        const int r = wr * 128 + i * 16 + (lane & 15);
        offA[i] = r * 32 + ((((lane >> 4) ^ (r >> 1)) & 3) << 3);
    }
#pragma unroll
    for (int j = 0; j < 4; ++j) {
        const int r = wc * 64 + j * 16 + (lane & 15);
        offB[j] = r * 32 + ((((lane >> 4) ^ (r >> 1)) & 3) << 3);
    }

    f32x4 acc[8][4];
#pragma unroll
    for (int i = 0; i < 8; ++i)
#pragma unroll
        for (int j = 0; j < 4; ++j)
            acc[i][j] = (f32x4){0.f, 0.f, 0.f, 0.f};

#define STG(NB, KB) do {                                                      \
        load_lds16((const u16*)(pAh + aof + (KB)), lds + (NB) + d0);          \
        load_lds16((const u16*)(pAh + ao2 + (KB)), lds + (NB) + d1);          \
        load_lds16((const u16*)(pB + bof + (KB)), lds + (NB) + O_B + d0);     \
        load_lds16((const u16*)(pB + bo2 + (KB)), lds + (NB) + O_B + d1);     \
        if constexpr (SPLIT) {                                                \
            load_lds16((const u16*)(pAl + aof + (KB)), lds + (NB) + O_AL + d0); \
            load_lds16((const u16*)(pAl + ao2 + (KB)), lds + (NB) + O_AL + d1); \
        }                                                                     \
    } while (0)

#define TERM(AF, BF) do {                                                     \
        __builtin_amdgcn_s_setprio(1);                                        \
        _Pragma("unroll")                                                     \
        for (int i = 0; i < 8; ++i)                                           \
            _Pragma("unroll")                                                 \
            for (int j = 0; j < 4; ++j)                                       \
                acc[i][j] = MFMA_F16(AF[i], BF[j], acc[i][j]);                \
        __builtin_amdgcn_s_setprio(0);                                        \
    } while (0)

    constexpr int NT = 32;

    STG(0, 0);

    for (int t = 0; t < NT; ++t) {
        const int cb = (t & 1) ? BUF : 0;
        const int nb = (t & 1) ? 0 : BUF;
        const long long kb = (long long)(t + 1) * 64;

        VMW0();
        SBAR();
        f16x8 b[4], ah[8], al[8];
#pragma unroll
        for (int j = 0; j < 4; ++j)
            b[j] = *(const f16x8*)(lds + cb + O_B + offB[j]);
#pragma unroll
        for (int i = 0; i < 8; ++i)
            ah[i] = *(const f16x8*)(lds + cb + offA[i]);
        if constexpr (SPLIT) {
#pragma unroll
            for (int i = 0; i < 8; ++i)
                al[i] = *(const f16x8*)(lds + cb + O_AL + offA[i]);
        }
        if (t + 1 < NT) STG(nb, kb);
        if constexpr (SPLIT) { LGKM8(); } else { LGKM0(); }
        SCHB();
        TERM(ah, b);
        if constexpr (SPLIT) {
            LGKM0(); SCHB();
            TERM(al, b);
        }
    }
#undef STG
#undef TERM

    const long long Cbase = z * sC;
#pragma unroll
    for (int i = 0; i < 8; ++i) {
        const int row0 = bm + wr * 128 + i * 16 + ((lane >> 4) << 2);
#pragma unroll
        for (int j = 0; j < 4; ++j) {
            const int col = bn + wc * 64 + j * 16 + (lane & 15);
#pragma unroll
            for (int e = 0; e < 4; ++e) {
                const float v = acc[i][j][e];
                const long long idx = Cbase + (long long)(row0 + e) * N + col;
                if constexpr (EPI == 0) {
                    Cf[idx] = v;
                } else if constexpr (EPI == 1) {
                    Ch[idx] = f2h(v + bias[col]);
                } else {
                    Cf[idx] = fmaxf(v, 0.f);
                }
            }
        }
    }
}

// ---------------------------------------------------------------------------
// R19 dense GEMM: faithful m201 8-phase port. 256x256, BK=64, 8 waves
// (2Mx4N), dbuf 128KB (buf = A 32KB + B 32KB), 2 K-tiles per iteration.
// Phase p in {0..3} computes buf0 quadrant (acc rows 2p,2p+1 x 4 cols x
// 2 subk = 16 MFMA); phases 4..7 the same on buf1. Per phase:
//   ds_read 4 A-frags (+8 B-frags at ph0/ph4, held in regs for the tile)
//   issue 2 staging loads -> [lgkm(8) if 12 reads] -> s_barrier ->
//   lgkmcnt(0)+sched_barrier -> setprio(1) 16 MFMA setprio(0) ->
//   [vmcnt(4) at ph3/ph7 only] -> s_barrier.
// Stage plan (T0=2it,T1,T2,T3): ph0-1: buf1.A(T1); ph2-3: buf0.B(T2);
// ph4-5: buf0.A(T2); ph6-7: buf1.B(T3). FIFO: vmcnt(4)@ph3 retires
// buf1.{B(prev ph6-7),A(ph0-1)} before ph4 reads buf1; vmcnt(4)@ph7
// retires buf0.{B,A}(T2) before next ph0. Never drains to 0 mid-loop.
// Free-check: every stage targets a region freed by an earlier
// end-of-phase barrier (B freed after its tile's first phase, A after
// its tile's 4th). Prologue {T0.B,T0.A,T1.B; vmcnt(4); barrier}
// reproduces steady state. Tail (it=NT2-1): skip T2/T3 stages, ph3
// waits vmcnt(0).
// Swizzle (R15 BK64, measured 0 conflicts): 128B rows, 8x16B slots,
// slot_phys = slot_log ^ (row&7), both staging source and ds_read.
// EPI: 0 = fp32 store, 2 = relu fp32 store.
// ---------------------------------------------------------------------------
template<int EPI>
__launch_bounds__(512, 2)
__global__ void gemm_p8(const u16* __restrict__ Am, const u16* __restrict__ Bm,
                        float* __restrict__ Cf,
                        int N, int gn, int gmn,
                        long long sA, long long sB, long long sC)
{
    constexpr int OB    = 16384;                 // B offset within buf (u16)
    constexpr int BUFSZ = 32768;                 // u16 per buffer (64KB)
    __shared__ __align__(16) u16 lds[2 * BUFSZ]; // 128KB

    const int tid  = threadIdx.x;
    const int lane = tid & 63;
    const int wv   = tid >> 6;
    const int wr   = wv >> 2, wc = wv & 3;

    const int d   = blockIdx.x;
    const int cpx = gridDim.x >> 3;
    const int swz = (d & 7) * cpx + (d >> 3);
    const long long z = swz / gmn;
    const int r_  = swz % gmn;
    const int bm  = (r_ / gn) * 256;
    const int bn  = (r_ % gn) * 256;

    const char* pA = (const char*)(Am + z * sA);
    const char* pB = (const char*)(Bm + z * sB);

    // staging: rr = tid>>3 (0..63), 8 slots, xor = rr&7 (128B rows).
    // chunk j covers row rr + j*64 (j=0..3); halves: j0,j1 = rows 0..127.
    const int rr  = tid >> 3;
    const int xcv = (tid & 7) ^ (rr & 7);
    long long aofs[4], bofs[4];
#pragma unroll
    for (int j = 0; j < 4; ++j) {
        aofs[j] = (long long)(bm + rr + j * 64) * 2048 + xcv * 16;
        bofs[j] = (long long)(bn + rr + j * 64) * 2048 + xcv * 16;
    }

    // frag ds_read offsets (u16 units), same swizzle
    int offA[8][2], offB[4][2];
#pragma unroll
    for (int i = 0; i < 8; ++i) {
        const int r = wr * 128 + i * 16 + (lane & 15);
#pragma unroll
        for (int s = 0; s < 2; ++s)
            offA[i][s] = r * 64 + ((((s * 4 + (lane >> 4)) ^ r) & 7) << 3);
    }
#pragma unroll
    for (int j = 0; j < 4; ++j) {
        const int r = wc * 64 + j * 16 + (lane & 15);
#pragma unroll
        for (int s = 0; s < 2; ++s)
            offB[j][s] = OB + r * 64 + ((((s * 4 + (lane >> 4)) ^ r) & 7) << 3);
    }

    f32x4 acc[8][4];
#pragma unroll
    for (int i = 0; i < 8; ++i)
#pragma unroll
        for (int j = 0; j < 4; ++j)
            acc[i][j] = (f32x4){0.f, 0.f, 0.f, 0.f};

    f16x8 bb[4][2];   // B frags of the current K-tile (live 4 phases)

#define STA(NB, J, KB) load_lds16((const u16*)(pA + aofs[J] + (KB)), \
                                  lds + (NB) + tid * 8 + (J) * 4096)
#define STB(NB, J, KB) load_lds16((const u16*)(pB + bofs[J] + (KB)), \
                                  lds + (NB) + OB + tid * 8 + (J) * 4096)
#define RD_BB(CB) do {                                                        \
        _Pragma("unroll")                                                     \
        for (int j = 0; j < 4; ++j) {                                         \
            bb[j][0] = *(const f16x8*)(lds + (CB) + offB[j][0]);              \
            bb[j][1] = *(const f16x8*)(lds + (CB) + offB[j][1]);              \
        }                                                                     \
    } while (0)
// one phase: quadrant I0/I0+1 of buffer CB; STAGES = staging stmts;
// FIRST: also read B frags; WAITST: vmcnt stmt after MFMA (or empty)
#define PHASE(CB, I0, FIRST, STAGES, WAITST) do {                             \
        if (FIRST) RD_BB(CB);                                                 \
        f16x8 a00 = *(const f16x8*)(lds + (CB) + offA[(I0)][0]);              \
        f16x8 a01 = *(const f16x8*)(lds + (CB) + offA[(I0)][1]);              \
        f16x8 a10 = *(const f16x8*)(lds + (CB) + offA[(I0) + 1][0]);          \
        f16x8 a11 = *(const f16x8*)(lds + (CB) + offA[(I0) + 1][1]);          \
        STAGES;                                                               \
        if (FIRST) LGKM8();                                                   \
        SBAR();                                                               \
        LGKM0(); SCHB();                                                      \
        __builtin_amdgcn_s_setprio(1);                                        \
        _Pragma("unroll")                                                     \
        for (int j = 0; j < 4; ++j) {                                         \
            acc[(I0)][j]     = MFMA_F16(a00, bb[j][0], acc[(I0)][j]);         \
            acc[(I0)][j]     = MFMA_F16(a01, bb[j][1], acc[(I0)][j]);         \
            acc[(I0) + 1][j] = MFMA_F16(a10, bb[j][0], acc[(I0) + 1][j]);     \
            acc[(I0) + 1][j] = MFMA_F16(a11, bb[j][1], acc[(I0) + 1][j]);     \
        }                                                                     \
        __builtin_amdgcn_s_setprio(0);                                        \
        WAITST;                                                               \
        SBAR();                                                               \
    } while (0)

    constexpr int NT2 = 8;       // iterations; 2 K-tiles (BK=64) each

    // prologue: T0.B, T0.A, T1.B (12 loads); vmcnt(4) leaves T1.B in flight.
    STB(0, 0, 0); STB(0, 1, 0); STB(0, 2, 0); STB(0, 3, 0);
    STA(0, 0, 0); STA(0, 1, 0); STA(0, 2, 0); STA(0, 3, 0);
    STB(BUFSZ, 0, 128); STB(BUFSZ, 1, 128); STB(BUFSZ, 2, 128); STB(BUFSZ, 3, 128);
    VMW4();
    SBAR();

    for (int it = 0; it < NT2; ++it) {
        const long long kb1 = (long long)(2 * it + 1) * 128;
        const long long kb2 = (long long)(2 * it + 2) * 128;
        const long long kb3 = (long long)(2 * it + 3) * 128;
        const bool st2 = (it + 1) < NT2;

        // ---- buf0 (tile 2it), phases 0..3
        PHASE(0, 0, true,  { STA(BUFSZ, 0, kb1); STA(BUFSZ, 1, kb1); }, );
        PHASE(0, 2, false, { STA(BUFSZ, 2, kb1); STA(BUFSZ, 3, kb1); }, );
        PHASE(0, 4, false, { if (st2) { STB(0, 0, kb2); STB(0, 1, kb2); } }, );
        PHASE(0, 6, false, { if (st2) { STB(0, 2, kb2); STB(0, 3, kb2); } },
              { if (st2) { VMW4(); } else { VMW0(); } });
        // ---- buf1 (tile 2it+1), phases 4..7
        PHASE(BUFSZ, 0, true,  { if (st2) { STA(0, 0, kb2); STA(0, 1, kb2); } }, );
        PHASE(BUFSZ, 2, false, { if (st2) { STA(0, 2, kb2); STA(0, 3, kb2); } }, );
        PHASE(BUFSZ, 4, false, { if (st2) { STB(BUFSZ, 0, kb3); STB(BUFSZ, 1, kb3); } }, );
        PHASE(BUFSZ, 6, false, { if (st2) { STB(BUFSZ, 2, kb3); STB(BUFSZ, 3, kb3); } },
              { if (st2) VMW4(); });
    }
#undef STA
#undef STB
#undef RD_BB
#undef PHASE

    // epilogue; C/D map: col = lane&15, row = (lane>>4)*4 + e  [m89/m91]
    const long long Cbase = z * sC;
#pragma unroll
    for (int i = 0; i < 8; ++i) {
        const int row0 = bm + wr * 128 + i * 16 + ((lane >> 4) << 2);
#pragma unroll
        for (int j = 0; j < 4; ++j) {
            const int col = bn + wc * 64 + j * 16 + (lane & 15);
#pragma unroll
            for (int e = 0; e < 4; ++e) {
                const float v = acc[i][j][e];
                const long long idx = Cbase + (long long)(row0 + e) * N + col;
                if constexpr (EPI == 0) Cf[idx] = v;
                else                    Cf[idx] = fmaxf(v, 0.f);
            }
        }
    }
}

// fp32 -> fp16 single, 4 elems/thread (p pre-pass)
__global__ void cvt_f16(const float* __restrict__ in, u16* __restrict__ o16,
                        long long n4)
{
    const long long i = (long long)blockIdx.x * 256 + threadIdx.x;
    if (i >= n4) return;
    const float4 v = ((const float4*)in)[i];
    ushort4 h;
    h.x = f2h(v.x); h.y = f2h(v.y); h.z = f2h(v.z); h.w = f2h(v.w);
    ((ushort4*)o16)[i] = h;
}

// fused q pre-pass: q_hi, q_lo (straight, fp16) and qT (transposed, fp16)
__global__ void fuse_cvt_q(const float* __restrict__ q, u16* __restrict__ hi,
                           u16* __restrict__ lo, u16* __restrict__ thi)
{
    __shared__ float t[32][33];
    const long long z = blockIdx.z;
    const long long base = z * 1048576;
    const int r0 = blockIdx.y * 32, c0 = blockIdx.x * 32;
    for (int j = threadIdx.y; j < 32; j += 8) {
        const float v = q[base + (long long)(r0 + j) * 1024 + c0 + threadIdx.x];
        t[j][threadIdx.x] = v;
        const long long o = base + (long long)(r0 + j) * 1024 + c0 + threadIdx.x;
        const u16 h = f2h(v);
        hi[o] = h;
        lo[o] = f2h(v - h2f(h));
    }
    __syncthreads();
    for (int j = threadIdx.y; j < 32; j += 8)
        thi[base + (long long)(c0 + j) * 1024 + r0 + threadIdx.x] = f2h(t[threadIdx.x][j]);
}

// Wt[c][r] = W[r][c], fp16 single
__global__ void transpose_cvt_w(const float* __restrict__ in, u16* __restrict__ hi)
{
    __shared__ float t[32][33];
    const int r0 = blockIdx.y * 32, c0 = blockIdx.x * 32;
    for (int j = threadIdx.y; j < 32; j += 8)
        t[j][threadIdx.x] = in[(long long)(r0 + j) * 1024 + c0 + threadIdx.x];
    __syncthreads();
    for (int j = threadIdx.y; j < 32; j += 8)
        hi[(long long)(c0 + j) * 1024 + r0 + threadIdx.x] = f2h(t[threadIdx.x][j]);
}

// row softmax (fp32 in, fp16 out)
__global__ void softmax_f16(const float* __restrict__ S, u16* __restrict__ A)
{
    const long long row = blockIdx.x;
    const float* r = S + row * (long long)LQ_N;
    const int t = threadIdx.x;
    float4 v = ((const float4*)r)[t];

    float m = fmaxf(fmaxf(v.x, v.y), fmaxf(v.z, v.w));
#pragma unroll
    for (int off = 32; off > 0; off >>= 1)
        m = fmaxf(m, __shfl_xor(m, off));

    __shared__ float red[4];
    const int lane = t & 63, wid = t >> 6;
    if (lane == 0) red[wid] = m;
    __syncthreads();
    m = fmaxf(fmaxf(red[0], red[1]), fmaxf(red[2], red[3]));
    __syncthreads();

    v.x = __expf(v.x - m); v.y = __expf(v.y - m);
    v.z = __expf(v.z - m); v.w = __expf(v.w - m);
    float s = v.x + v.y + v.z + v.w;
#pragma unroll
    for (int off = 32; off > 0; off >>= 1)
        s += __shfl_xor(s, off);
    if (lane == 0) red[wid] = s;
    __syncthreads();
    s = red[0] + red[1] + red[2] + red[3];

    const float inv = 1.0f / s;
    ushort4 o;
    o.x = f2h(v.x * inv); o.y = f2h(v.y * inv);
    o.z = f2h(v.z * inv); o.w = f2h(v.w * inv);
    ((ushort4*)(A + row * (long long)LQ_N))[t] = o;
}

// ---------------------------------------------------------------------------
// Fallback fp32 path (round-1, verified; needs only 128 MB ws)
// ---------------------------------------------------------------------------
#define BM 128
#define BN 128
#define BK 8
#define TM 8
#define TN 8

template<bool TRANSB, bool BIAS, bool RELU>
__launch_bounds__(256)
__global__ void gemm_k(const float* __restrict__ A, const float* __restrict__ Bmat,
                       const float* __restrict__ bias, float* __restrict__ C,
                       int M, int N, int K,
                       long long sA, long long sB, long long sC)
{
    __shared__ float As[BK][BM];
    __shared__ float Bs[BK][BN];
    const int tid = threadIdx.x;
    const int tx = tid & 15;
    const int ty = tid >> 4;
    const int bn = blockIdx.x * BN;
    const int bm = blockIdx.y * BM;
    const long long z = blockIdx.z;
    A += z * sA; Bmat += z * sB; C += z * sC;
    float acc[TM][TN];
#pragma unroll
    for (int i = 0; i < TM; i++)
#pragma unroll
        for (int j = 0; j < TN; j++) acc[i][j] = 0.f;
    const int arow = tid >> 1;
    const int acol = (tid & 1) * 4;
    const int bk_n = tid >> 5;
    const int bn_n = (tid & 31) * 4;
    for (int k0 = 0; k0 < K; k0 += BK) {
        float4 a4 = *(const float4*)&A[(long long)(bm + arow) * K + k0 + acol];
        As[acol + 0][arow] = a4.x; As[acol + 1][arow] = a4.y;
        As[acol + 2][arow] = a4.z; As[acol + 3][arow] = a4.w;
        if (TRANSB) {
            float4 b4 = *(const float4*)&Bmat[(long long)(bn + arow) * K + k0 + acol];
            Bs[acol + 0][arow] = b4.x; Bs[acol + 1][arow] = b4.y;
            Bs[acol + 2][arow] = b4.z; Bs[acol + 3][arow] = b4.w;
        } else {
            float4 b4 = *(const float4*)&Bmat[(long long)(k0 + bk_n) * N + bn + bn_n];
            *(float4*)&Bs[bk_n][bn_n] = b4;
        }
        __syncthreads();
#pragma unroll
        for (int k = 0; k < BK; k++) {
            float a[TM], b[TN];
            *(float4*)&a[0] = *(const float4*)&As[k][ty * TM];
            *(float4*)&a[4] = *(const float4*)&As[k][ty * TM + 4];
            *(float4*)&b[0] = *(const float4*)&Bs[k][tx * TN];
            *(float4*)&b[4] = *(const float4*)&Bs[k][tx * TN + 4];
#pragma unroll
            for (int i = 0; i < TM; i++)
#pragma unroll
                for (int j = 0; j < TN; j++)
                    acc[i][j] = fmaf(a[i], b[j], acc[i][j]);
        }
        __syncthreads();
    }
#pragma unroll
    for (int i = 0; i < TM; i++) {
        const int row = bm + ty * TM + i;
#pragma unroll
        for (int j = 0; j < TN; j += 4) {
            const int col = bn + tx * TN + j;
            float4 v;
            v.x = acc[i][j + 0]; v.y = acc[i][j + 1];
            v.z = acc[i][j + 2]; v.w = acc[i][j + 3];
            if (BIAS) {
                v.x += bias[col + 0]; v.y += bias[col + 1];
                v.z += bias[col + 2]; v.w += bias[col + 3];
            }
            if (RELU) {
                v.x = fmaxf(v.x, 0.f); v.y = fmaxf(v.y, 0.f);
                v.z = fmaxf(v.z, 0.f); v.w = fmaxf(v.w, 0.f);
            }
            *(float4*)&C[(long long)row * N + col] = v;
        }
    }
}

__global__ void softmax_k(float* __restrict__ S)
{
    const long long row = blockIdx.x;
    float* r = S + row * (long long)LQ_N;
    const int t = threadIdx.x;
    float4 v = ((float4*)r)[t];
    float m = fmaxf(fmaxf(v.x, v.y), fmaxf(v.z, v.w));
#pragma unroll
    for (int off = 32; off > 0; off >>= 1)
        m = fmaxf(m, __shfl_xor(m, off));
    __shared__ float red[4];
    const int lane = t & 63, wid = t >> 6;
    if (lane == 0) red[wid] = m;
    __syncthreads();
    m = fmaxf(fmaxf(red[0], red[1]), fmaxf(red[2], red[3]));
    __syncthreads();
    v.x = __expf(v.x - m); v.y = __expf(v.y - m);
    v.z = __expf(v.z - m); v.w = __expf(v.w - m);
    float s = v.x + v.y + v.z + v.w;
#pragma unroll
    for (int off = 32; off > 0; off >>= 1)
        s += __shfl_xor(s, off);
    if (lane == 0) red[wid] = s;
    __syncthreads();
    s = red[0] + red[1] + red[2] + red[3];
    const float inv = 1.0f / s;
    v.x *= inv; v.y *= inv; v.z *= inv; v.w *= inv;
    ((float4*)r)[t] = v;
}

extern "C" void kernel_launch(void* const* d_in, const int* in_sizes, int n_in,
                              void* d_out, int out_size, void* d_ws, size_t ws_size,
                              hipStream_t stream)
{
    const float* p    = (const float*)d_in[0];
    const float* q    = (const float*)d_in[1];
    const float* W    = (const float*)d_in[2];
    const float* bias = (const float*)d_in[3];
    float* out = (float*)d_out;

    const size_t MB32 = 33554432ull;                 // 32 MB unit
    const size_t NEED = 5 * MB32 + 2097152ull;       // 162 MB

    if (ws_size >= NEED) {
        char* w = (char*)d_ws;
        u16* p16   = (u16*)(w + 0 * MB32);
        u16* q_hi  = (u16*)(w + 1 * MB32);
        u16* q_lo  = (u16*)(w + 2 * MB32);
        u16* keys  = (u16*)(w + 3 * MB32);
        u16* qT    = (u16*)(w + 4 * MB32);
        u16* Wt    = (u16*)(w + 5 * MB32);
        float* scores = (float*)(w + 1 * MB32);  // reuses q_hi/q_lo after GEMM1
        u16* attn     = (u16*)(w + 0 * MB32);    // reuses p16 after GEMM2

        const long long n4 = (long long)B_N * LQ_N * H_N / 4;
        cvt_f16<<<dim3((unsigned)(n4 / 256)), 256, 0, stream>>>(p, p16, n4);
        fuse_cvt_q<<<dim3(32, 32, B_N), dim3(32, 8), 0, stream>>>(q, q_hi, q_lo, qT);
        transpose_cvt_w<<<dim3(32, 32, 1), dim3(32, 8), 0, stream>>>(W, Wt);

        // keys = (q_hi + q_lo) @ Wt + b : BK32 split, grid 256 (R15 config).
        gemm2t<true, 1><<<256, 512, 0, stream>>>(
            q_hi, q_lo, Wt, bias, nullptr, keys,
            H_N, /*gn=*/4, /*gmn=*/256, 0, 0, 0);

        // scores[b] = p16[b] @ keys[b]^T : 8-phase dense.
        gemm_p8<0><<<256, 512, 0, stream>>>(
            p16, keys, scores,
            LQ_N, /*gn=*/4, /*gmn=*/16,
            (long long)LP_N * H_N, (long long)LQ_N * H_N, (long long)LP_N * LQ_N);

        softmax_f16<<<B_N * LP_N, 256, 0, stream>>>(scores, attn);

        // out[b] = relu(attn[b] @ q[b]) : 8-phase dense.
        gemm_p8<2><<<256, 512, 0, stream>>>(
            attn, qT, out,
            H_N, /*gn=*/4, /*gmn=*/16,
            (long long)LP_N * LQ_N, (long long)H_N * LQ_N, (long long)LP_N * H_N);
    } else {
        float* keys   = (float*)d_ws;
        float* scores = keys + (long long)B_N * LQ_N * H_N;

        gemm_k<false, true, false><<<dim3(H_N / BN, (B_N * LQ_N) / BM, 1), 256, 0, stream>>>(
            q, W, bias, keys, B_N * LQ_N, H_N, H_N, 0, 0, 0);
        gemm_k<true, false, false><<<dim3(LQ_N / BN, LP_N / BM, B_N), 256, 0, stream>>>(
            p, keys, nullptr, scores, LP_N, LQ_N, H_N,
            (long long)LP_N * H_N, (long long)LQ_N * H_N, (long long)LP_N * LQ_N);
        softmax_k<<<B_N * LP_N, 256, 0, stream>>>(scores);
        gemm_k<false, false, true><<<dim3(H_N / BN, LP_N / BM, B_N), 256, 0, stream>>>(
            scores, q, nullptr, out, LP_N, H_N, LQ_N,
            (long long)LP_N * LQ_N, (long long)LQ_N * H_N, (long long)LP_N * H_N);
    }
}